// Round 8
// baseline (247.004 us; speedup 1.0000x reference)
//
#include <hip/hip_runtime.h>
#include <hip/hip_bf16.h>
#include <cmath>

// ---------------------------------------------------------------------------
// NPerTokenSwishGLU_Basis — fused f16-MFMA implementation (gfx950), round 15.
//
// R14 post-mortem: lgkmcnt-only barrier null (48.9us). Cross-round pattern:
// more waves null, fewer barriers null, I$ null, barrier semantics null,
// independent blocks small win -> the untested mechanism is prefetch
// DISTANCE: all rounds issued pa/xf <1 iteration before use vs 200-900cy
// L2/L3 latency. R15: distance-2 prefetch via even/odd register sets
// (paE/paO, xfE/xfO; static names, rule-#20-safe), fixed buffer parity
// (even->Wt0, odd->Wt1), peeled 2-iteration tails (no OOB issues).
// up: pa+xf distance-2; down: pa distance-2 (hf is L2-warm).
// ---------------------------------------------------------------------------

typedef _Float16 half8 __attribute__((ext_vector_type(8)));
typedef _Float16 half4 __attribute__((ext_vector_type(4)));
typedef float    f32x4 __attribute__((ext_vector_type(4)));
typedef float    f32x2 __attribute__((ext_vector_type(2)));

#define MFMA_F16  __builtin_amdgcn_mfma_f32_16x16x32_f16
#define MFMA16    __builtin_amdgcn_mfma_f32_16x16x16f16

// LDS-only barrier: drain DS ops, leave global loads in flight (T4).
#define LDS_BARRIER()                                           \
    do {                                                        \
        asm volatile("s_waitcnt lgkmcnt(0)" ::: "memory");      \
        __builtin_amdgcn_s_barrier();                           \
    } while (0)

static constexpr size_t OFF_P1  = 0;            // 16 MiB; Rp overlay (down)
static constexpr size_t OFF_P2  = 16777216;     // 16 MiB; Np overlay (down, 1 MiB)
static constexpr size_t OFF_P3n = 17825792;     // 16 MiB at 17 MiB (after Np)
static constexpr size_t OFF_XA  = 33554432;     // 2 MiB at 32 MiB
static constexpr size_t OFF_U2  = 35651584;     // 4 MiB at 34 MiB
static constexpr size_t OFF_S   = 39845888;     // 4 MiB at 38 MiB (top 42 MiB)
static constexpr size_t WS_FAST = 54525952;     // 52 MiB (proven)

// ---------------------------------------------------------------------------
// prep (two-sided coalesced transpose), 32x32 tiles (R13):
//   z=0,1: wg/wu (K,512,1024)=[k][d][f] -> P[f][d][k]
//   z=2  : wd    (K,1024,512)=[k][f][d] -> P3[d][f][k]
// ---------------------------------------------------------------------------
__global__ __launch_bounds__(256) void prep_basis_all(
    const float* __restrict__ wg, const float* __restrict__ wu,
    const float* __restrict__ wd,
    _Float16* __restrict__ P1, _Float16* __restrict__ P2,
    _Float16* __restrict__ P3, int zoff)
{
    int z = blockIdx.y + zoff;
    const float* src = (z == 0) ? wg : (z == 1) ? wu : wd;
    _Float16*    dst = (z == 0) ? P1 : (z == 1) ? P2 : P3;
    int Amin = (z == 2) ? 1024 : 512;    // minor-dim size
    int Bmaj = (z == 2) ? 512 : 1024;    // major-dim size
    int nM = Bmaj >> 5;
    int m0 = (blockIdx.x / nM) * 32;     // minor base
    int M0 = (blockIdx.x % nM) * 32;     // major base

    __shared__ float S[16 * 1088];       // [k][row*34 + col]
    int t = threadIdx.x;

    int row = t >> 3;                    // 0..31 (minor row)
    int cg  = t & 7;                     // 0..7 (16B col group)
#pragma unroll
    for (int k = 0; k < 16; ++k) {
        f32x4 v = *(const f32x4*)(
            src + (size_t)k * Amin * Bmaj + (size_t)(m0 + row) * Bmaj + M0 + cg * 4);
        f32x2 lo = { v[0], v[1] };
        f32x2 hi = { v[2], v[3] };
        *(f32x2*)(&S[k * 1088 + row * 34 + cg * 4])     = lo;
        *(f32x2*)(&S[k * 1088 + row * 34 + cg * 4 + 2]) = hi;
    }
    __syncthreads();

    int mn = t & 31, mjq = t >> 5;
#pragma unroll
    for (int q = 0; q < 4; ++q) {
        int mj = q * 8 + mjq;
        half8 v0, v1;
#pragma unroll
        for (int k = 0; k < 8; ++k) v0[k] = (_Float16)S[k * 1088 + mn * 34 + mj];
#pragma unroll
        for (int k = 0; k < 8; ++k) v1[k] = (_Float16)S[(k + 8) * 1088 + mn * 34 + mj];
        _Float16* out = dst + ((size_t)(M0 + mj) * Amin + m0 + mn) * 16;
        *(half8*)out       = v0;
        *(half8*)(out + 8) = v1;
    }
}

// ---------------------------------------------------------------------------
// prep_x: x fp32 [b][l][d] -> XA f16 [l][d>>3][b][8]
// grid 256 = 128 l x 2 b-halves, 256 threads.
// ---------------------------------------------------------------------------
__global__ __launch_bounds__(256) void prep_x(
    const float* __restrict__ x, _Float16* __restrict__ XA)
{
    int l = blockIdx.x >> 1, bh = blockIdx.x & 1;
    __shared__ __align__(16) _Float16 XT[8][524];
    int t = threadIdx.x;

    int bl = t >> 5, q = t & 31;          // b-local 0..7, q 0..31
    int b = bh * 8 + bl;
#pragma unroll
    for (int j = 0; j < 4; ++j) {
        f32x4 v = *(const f32x4*)(x + ((size_t)(b * 128 + l) * 512 + j * 128 + q * 4));
#pragma unroll
        for (int i = 0; i < 4; ++i)
            XT[bl][j * 128 + q * 4 + i] = (_Float16)v[i];
    }
    __syncthreads();

    int c = t >> 2, bi = t & 3;           // c 0..63
#pragma unroll
    for (int s = 0; s < 2; ++s) {
        int blw = bi * 2 + s;             // 0..7
        half8 h = *(const half8*)(&XT[blw][c * 8]);
        *(half8*)(XA + (((size_t)(l * 64 + c) * 16 + bh * 8 + blw) * 8)) = h;
    }
}

// ---------------------------------------------------------------------------
// up_split (R15): 1024 blocks = mh(2) x 8 lg x 64 f-tiles, 256 thr / 4 waves.
// Distance-2 prefetch: paE/paO (pa), xfE/xfO (xf); even->Wt0, odd->Wt1.
// Main loop = 7 double-iterations (it 0..13); peeled it=14,15; tail consume.
// ---------------------------------------------------------------------------
__global__ __launch_bounds__(256, 4) void up_split(
    const _Float16* __restrict__ P1, const _Float16* __restrict__ P2,
    const _Float16* __restrict__ XA,
    const float* __restrict__ tc1, const float* __restrict__ tc2,
    const float* __restrict__ usp, const float* __restrict__ vsp,
    _Float16* __restrict__ U2, _Float16* __restrict__ S)
{
    int bid = blockIdx.x;
    int mh = bid >> 9;                  // 0: gate/u, 1: up/v
    int lg = (bid >> 6) & 7;
    int f0 = (bid & 63) * 16;
    int tid = threadIdx.x;
    int w = tid >> 6, lane = tid & 63;
    int n = lane & 15, kc = lane >> 4;

    const _Float16* P  = mh ? P2 : P1;
    const float*    tc = mh ? tc2 : tc1;

    __shared__ __align__(16) _Float16 Wt[2][16 * 584]; // [buf][l*584+f*36+d]
    __shared__ float CN[256];
    _Float16* Wt0 = &Wt[0][0];
    _Float16* Wt1 = &Wt[1][0];

    // element-unit base pointers (advance +512 per 32-d chunk)
    const _Float16* pP  = P + ((size_t)(f0 + w * 4) * 512 + n) * 16 + kc * 4;
    const _Float16* pXA = XA + (((size_t)(lg * 16 + w * 4) * 64 + kc) * 16 + n) * 8;

    half4 paE[4][2], paO[4][2];
    half8 xfE[4], xfO[4];
    // ---- prologue: issue pa(0)->paE, pa(1)->paO, xf(0)->xfE ----
#pragma unroll
    for (int fl = 0; fl < 4; ++fl)
#pragma unroll
        for (int dg = 0; dg < 2; ++dg) {
            paE[fl][dg] = *(const half4*)(pP + fl * 8192 + dg * 256);
            paO[fl][dg] = *(const half4*)(pP + 512 + fl * 8192 + dg * 256);
        }
#pragma unroll
    for (int li = 0; li < 4; ++li)
        xfE[li] = *(const half8*)(pXA + li * 8192);
    const _Float16* qP  = pP + 1024;    // next issue: pa(2)
    const _Float16* qXA = pXA + 512;    // next issue: xf(1)

    if (tid < 16) {
        const float* row = tc + (size_t)(lg * 16 + tid) * 16;
        float e[16], m = -1e30f, sum = 0.f;
#pragma unroll
        for (int k = 0; k < 16; ++k) m = fmaxf(m, row[k]);
#pragma unroll
        for (int k = 0; k < 16; ++k) { e[k] = __expf(row[k] - m); sum += e[k]; }
        float r = 1.f / sum;
#pragma unroll
        for (int k = 0; k < 16; ++k) CN[tid * 16 + k] = e[k] * r;
    }
    __syncthreads();

    half4 cf;
#pragma unroll
    for (int j = 0; j < 4; ++j)
        cf[j] = (_Float16)CN[n * 16 + kc * 4 + j];

    f32x4 zf = { 0.f, 0.f, 0.f, 0.f };
    f32x4 aU[4];
#pragma unroll
    for (int i = 0; i < 4; ++i) aU[i] = zf;
    float nsq[4] = { 0.f, 0.f, 0.f, 0.f };

#pragma unroll 1
    for (int it2 = 0; it2 < 7; ++it2) {
        // ============ even it = 2*it2: mix->Wt0, consume(it-1) Wt1/xfO ======
#pragma unroll
        for (int fl = 0; fl < 4; ++fl) {
            int f_l = w * 4 + fl;
#pragma unroll
            for (int dg = 0; dg < 2; ++dg) {
                f32x4 c1 = MFMA16(paE[fl][dg], cf, zf, 0, 0, 0);
                nsq[fl] += c1[0] * c1[0] + c1[1] * c1[1]
                         + c1[2] * c1[2] + c1[3] * c1[3];
                half4 h1 = { (_Float16)c1[0], (_Float16)c1[1],
                             (_Float16)c1[2], (_Float16)c1[3] };
                *(half4*)(&Wt0[n * 584 + f_l * 36 + dg * 16 + kc * 4]) = h1;
            }
        }
        // issue paE = pa(it+2)
#pragma unroll
        for (int fl = 0; fl < 4; ++fl)
#pragma unroll
            for (int dg = 0; dg < 2; ++dg)
                paE[fl][dg] = *(const half4*)(qP + fl * 8192 + dg * 256);
        qP += 512;
        if (it2 > 0) {
#pragma unroll
            for (int li = 0; li < 4; ++li) {
                int l = w * 4 + li;
                half8 wU = *(const half8*)(&Wt1[l * 584 + n * 36 + kc * 8]);
                aU[li] = MFMA_F16(xfO[li], wU, aU[li], 0, 0, 0);
            }
        }
        // issue xfO = xf(it+1)
#pragma unroll
        for (int li = 0; li < 4; ++li)
            xfO[li] = *(const half8*)(qXA + li * 8192);
        qXA += 512;
        LDS_BARRIER();
        // ============ odd it = 2*it2+1: mix->Wt1, consume(it-1) Wt0/xfE =====
#pragma unroll
        for (int fl = 0; fl < 4; ++fl) {
            int f_l = w * 4 + fl;
#pragma unroll
            for (int dg = 0; dg < 2; ++dg) {
                f32x4 c1 = MFMA16(paO[fl][dg], cf, zf, 0, 0, 0);
                nsq[fl] += c1[0] * c1[0] + c1[1] * c1[1]
                         + c1[2] * c1[2] + c1[3] * c1[3];
                half4 h1 = { (_Float16)c1[0], (_Float16)c1[1],
                             (_Float16)c1[2], (_Float16)c1[3] };
                *(half4*)(&Wt1[n * 584 + f_l * 36 + dg * 16 + kc * 4]) = h1;
            }
        }
        // issue paO = pa(it+2)
#pragma unroll
        for (int fl = 0; fl < 4; ++fl)
#pragma unroll
            for (int dg = 0; dg < 2; ++dg)
                paO[fl][dg] = *(const half4*)(qP + fl * 8192 + dg * 256);
        qP += 512;
#pragma unroll
        for (int li = 0; li < 4; ++li) {
            int l = w * 4 + li;
            half8 wU = *(const half8*)(&Wt0[l * 584 + n * 36 + kc * 8]);
            aU[li] = MFMA_F16(xfE[li], wU, aU[li], 0, 0, 0);
        }
        // issue xfE = xf(it+2)
#pragma unroll
        for (int li = 0; li < 4; ++li)
            xfE[li] = *(const half8*)(qXA + li * 8192);
        qXA += 512;
        LDS_BARRIER();
    }
    // ---- peel it = 14 (even): mix->Wt0; consume(13) Wt1/xfO; xfO = xf(15)
#pragma unroll
    for (int fl = 0; fl < 4; ++fl) {
        int f_l = w * 4 + fl;
#pragma unroll
        for (int dg = 0; dg < 2; ++dg) {
            f32x4 c1 = MFMA16(paE[fl][dg], cf, zf, 0, 0, 0);
            nsq[fl] += c1[0] * c1[0] + c1[1] * c1[1]
                     + c1[2] * c1[2] + c1[3] * c1[3];
            half4 h1 = { (_Float16)c1[0], (_Float16)c1[1],
                         (_Float16)c1[2], (_Float16)c1[3] };
            *(half4*)(&Wt0[n * 584 + f_l * 36 + dg * 16 + kc * 4]) = h1;
        }
    }
#pragma unroll
    for (int li = 0; li < 4; ++li) {
        int l = w * 4 + li;
        half8 wU = *(const half8*)(&Wt1[l * 584 + n * 36 + kc * 8]);
        aU[li] = MFMA_F16(xfO[li], wU, aU[li], 0, 0, 0);
    }
#pragma unroll
    for (int li = 0; li < 4; ++li)
        xfO[li] = *(const half8*)(qXA + li * 8192);
    LDS_BARRIER();
    // ---- peel it = 15 (odd): mix->Wt1; consume(14) Wt0/xfE
#pragma unroll
    for (int fl = 0; fl < 4; ++fl) {
        int f_l = w * 4 + fl;
#pragma unroll
        for (int dg = 0; dg < 2; ++dg) {
            f32x4 c1 = MFMA16(paO[fl][dg], cf, zf, 0, 0, 0);
            nsq[fl] += c1[0] * c1[0] + c1[1] * c1[1]
                     + c1[2] * c1[2] + c1[3] * c1[3];
            half4 h1 = { (_Float16)c1[0], (_Float16)c1[1],
                         (_Float16)c1[2], (_Float16)c1[3] };
            *(half4*)(&Wt1[n * 584 + f_l * 36 + dg * 16 + kc * 4]) = h1;
        }
    }
#pragma unroll
    for (int li = 0; li < 4; ++li) {
        int l = w * 4 + li;
        half8 wU = *(const half8*)(&Wt0[l * 584 + n * 36 + kc * 8]);
        aU[li] = MFMA_F16(xfE[li], wU, aU[li], 0, 0, 0);
    }
    LDS_BARRIER();
    // ---- tail consume(15): Wt1 with xfO = xf(15) ----
#pragma unroll
    for (int li = 0; li < 4; ++li) {
        int l = w * 4 + li;
        half8 wU = *(const half8*)(&Wt1[l * 584 + n * 36 + kc * 8]);
        aU[li] = MFMA_F16(xfO[li], wU, aU[li], 0, 0, 0);
    }

    // ---- norm reduce ----
#pragma unroll
    for (int fl = 0; fl < 4; ++fl) {
        float vU = nsq[fl];
        vU += __shfl_xor(vU, 16); vU += __shfl_xor(vU, 32);
        if (kc == 0) CN[n * 16 + w * 4 + fl] = vU;
    }
    __syncthreads();

    int f = f0 + n;
    float sc = mh ? (fabsf(vsp[f]) * 22.627416997969522f)   // vs = |vsp|*sqrt(512)
                  : fabsf(usp[f]);                          // us = |usp|
    _Float16* Out = mh ? S : U2;
#pragma unroll
    for (int li = 0; li < 4; ++li) {
        int lgl = lg * 16 + w * 4 + li;
        float r1 = 1.f / fmaxf(sqrtf(CN[(w * 4 + li) * 16 + n]), 1e-12f);
#pragma unroll
        for (int i = 0; i < 4; ++i) {
            float val = aU[li][i] * r1 * sc;       // us*u'  or  vs*v'
            if (mh) val = val / (1.f + __expf(-val));   // silu(vs*v')
            // layout [l][f>>3][b][8]
            Out[(((size_t)lgl * 128 + (f >> 3)) * 16 + kc * 4 + i) * 8 + (f & 7)] =
                (_Float16)val;
        }
    }
}

// ---------------------------------------------------------------------------
// down_fast (R15): 1024 blocks = 4 f-quarters x 8 lg x 32 d-tiles.
// Distance-2 prefetch for pa (paE/paO); hf stays distance-1 (L2-warm S/U2).
// Main loop = 3 double-iterations (it 0..5); peeled it=6,7; tail consume.
// ---------------------------------------------------------------------------
__global__ __launch_bounds__(256, 4) void down_fast(
    const _Float16* __restrict__ P3, const float* __restrict__ tc3,
    const _Float16* __restrict__ S, const _Float16* __restrict__ U2,
    float* __restrict__ Rp, float* __restrict__ Np)
{
    int zh = blockIdx.x >> 8;          // 0..3
    int rem = blockIdx.x & 255;
    int lg = rem >> 5;
    int d0 = (rem & 31) * 16;
    int tid = threadIdx.x;
    int w = tid >> 6, lane = tid & 63;
    int n = lane & 15, kc = lane >> 4;

    __shared__ __align__(16) _Float16 Wt[2][16 * 584];    // [buf][l*584 + d*36 + f]
    __shared__ float CN[256];
    _Float16* Wt0 = &Wt[0][0];
    _Float16* Wt1 = &Wt[1][0];

    // element-unit base pointers (advance +512 per 32-f chunk)
    const _Float16* pP3 = P3 + ((size_t)(d0 + w * 4) * 1024 + zh * 256 + n) * 16 + kc * 4;
    size_t hoff = (((size_t)(lg * 16 + w * 4) * 128 + zh * 32 + kc) * 16 + n) * 8;
    const _Float16* pS = S + hoff;
    const _Float16* pU = U2 + hoff;

    half4 paE[4][2], paO[4][2];
    // ---- prologue: pa(0)->paE, pa(1)->paO ----
#pragma unroll
    for (int dl = 0; dl < 4; ++dl)
#pragma unroll
        for (int fg = 0; fg < 2; ++fg) {
            paE[dl][fg] = *(const half4*)(pP3 + dl * 16384 + fg * 256);
            paO[dl][fg] = *(const half4*)(pP3 + 512 + dl * 16384 + fg * 256);
        }
    const _Float16* qP3 = pP3 + 1024;   // next issue: pa(2)

    if (tid < 16) {
        const float* row = tc3 + (size_t)(lg * 16 + tid) * 16;
        float e[16], m = -1e30f, sum = 0.f;
#pragma unroll
        for (int k = 0; k < 16; ++k) m = fmaxf(m, row[k]);
#pragma unroll
        for (int k = 0; k < 16; ++k) { e[k] = __expf(row[k] - m); sum += e[k]; }
        float r = 1.f / sum;
#pragma unroll
        for (int k = 0; k < 16; ++k) CN[tid * 16 + k] = e[k] * r;
    }
    __syncthreads();

    half4 cf3;
#pragma unroll
    for (int j = 0; j < 4; ++j)
        cf3[j] = (_Float16)CN[n * 16 + kc * 4 + j];

    f32x4 zf = { 0.f, 0.f, 0.f, 0.f };
    f32x4 aO[4];
#pragma unroll
    for (int i = 0; i < 4; ++i) aO[i] = zf;
    float nsqD[4] = { 0.f, 0.f, 0.f, 0.f };
    half8 hf[4];

#pragma unroll 1
    for (int it2 = 0; it2 < 3; ++it2) {
        // ============ even it = 2*it2: mix->Wt0, consume(it-1) Wt1 ==========
#pragma unroll
        for (int dl = 0; dl < 4; ++dl) {
            int d_l = w * 4 + dl;
#pragma unroll
            for (int fg = 0; fg < 2; ++fg) {
                f32x4 cw = MFMA16(paE[dl][fg], cf3, zf, 0, 0, 0);
                nsqD[dl] += cw[0] * cw[0] + cw[1] * cw[1]
                          + cw[2] * cw[2] + cw[3] * cw[3];
                half4 h4 = { (_Float16)cw[0], (_Float16)cw[1],
                             (_Float16)cw[2], (_Float16)cw[3] };
                *(half4*)(&Wt0[n * 584 + d_l * 36 + fg * 16 + kc * 4]) = h4;
            }
        }
#pragma unroll
        for (int dl = 0; dl < 4; ++dl)
#pragma unroll
            for (int fg = 0; fg < 2; ++fg)
                paE[dl][fg] = *(const half4*)(qP3 + dl * 16384 + fg * 256);
        qP3 += 512;
        if (it2 > 0) {
#pragma unroll
            for (int li = 0; li < 4; ++li) {
                int l = w * 4 + li;
                half8 wf = *(const half8*)(&Wt1[l * 584 + n * 36 + kc * 8]);
                aO[li] = MFMA_F16(hf[li], wf, aO[li], 0, 0, 0);
            }
        }
#pragma unroll
        for (int li = 0; li < 4; ++li) {
            half8 s8 = *(const half8*)(pS + li * 16384);
            half8 u8 = *(const half8*)(pU + li * 16384);
            hf[li] = s8 * u8;
        }
        pS += 512;
        pU += 512;
        LDS_BARRIER();
        // ============ odd it = 2*it2+1: mix->Wt1, consume(it-1) Wt0 =========
#pragma unroll
        for (int dl = 0; dl < 4; ++dl) {
            int d_l = w * 4 + dl;
#pragma unroll
            for (int fg = 0; fg < 2; ++fg) {
                f32x4 cw = MFMA16(paO[dl][fg], cf3, zf, 0, 0, 0);
                nsqD[dl] += cw[0] * cw[0] + cw[1] * cw[1]
                          + cw[2] * cw[2] + cw[3] * cw[3];
                half4 h4 = { (_Float16)cw[0], (_Float16)cw[1],
                             (_Float16)cw[2], (_Float16)cw[3] };
                *(half4*)(&Wt1[n * 584 + d_l * 36 + fg * 16 + kc * 4]) = h4;
            }
        }
#pragma unroll
        for (int dl = 0; dl < 4; ++dl)
#pragma unroll
            for (int fg = 0; fg < 2; ++fg)
                paO[dl][fg] = *(const half4*)(qP3 + dl * 16384 + fg * 256);
        qP3 += 512;
#pragma unroll
        for (int li = 0; li < 4; ++li) {
            int l = w * 4 + li;
            half8 wf = *(const half8*)(&Wt0[l * 584 + n * 36 + kc * 8]);
            aO[li] = MFMA_F16(hf[li], wf, aO[li], 0, 0, 0);
        }
#pragma unroll
        for (int li = 0; li < 4; ++li) {
            half8 s8 = *(const half8*)(pS + li * 16384);
            half8 u8 = *(const half8*)(pU + li * 16384);
            hf[li] = s8 * u8;
        }
        pS += 512;
        pU += 512;
        LDS_BARRIER();
    }
    // ---- peel it = 6 (even): mix->Wt0; consume(5) Wt1; load hf(6)
#pragma unroll
    for (int dl = 0; dl < 4; ++dl) {
        int d_l = w * 4 + dl;
#pragma unroll
        for (int fg = 0; fg < 2; ++fg) {
            f32x4 cw = MFMA16(paE[dl][fg], cf3, zf, 0, 0, 0);
            nsqD[dl] += cw[0] * cw[0] + cw[1] * cw[1]
                      + cw[2] * cw[2] + cw[3] * cw[3];
            half4 h4 = { (_Float16)cw[0], (_Float16)cw[1],
                         (_Float16)cw[2], (_Float16)cw[3] };
            *(half4*)(&Wt0[n * 584 + d_l * 36 + fg * 16 + kc * 4]) = h4;
        }
    }
#pragma unroll
    for (int li = 0; li < 4; ++li) {
        int l = w * 4 + li;
        half8 wf = *(const half8*)(&Wt1[l * 584 + n * 36 + kc * 8]);
        aO[li] = MFMA_F16(hf[li], wf, aO[li], 0, 0, 0);
    }
#pragma unroll
    for (int li = 0; li < 4; ++li) {
        half8 s8 = *(const half8*)(pS + li * 16384);
        half8 u8 = *(const half8*)(pU + li * 16384);
        hf[li] = s8 * u8;
    }
    pS += 512;
    pU += 512;
    LDS_BARRIER();
    // ---- peel it = 7 (odd): mix->Wt1; consume(6) Wt0; load hf(7)
#pragma unroll
    for (int dl = 0; dl < 4; ++dl) {
        int d_l = w * 4 + dl;
#pragma unroll
        for (int fg = 0; fg < 2; ++fg) {
            f32x4 cw = MFMA16(paO[dl][fg], cf3, zf, 0, 0, 0);
            nsqD[dl] += cw[0] * cw[0] + cw[1] * cw[1]
                      + cw[2] * cw[2] + cw[3] * cw[3];
            half4 h4 = { (_Float16)cw[0], (_Float16)cw[1],
                         (_Float16)cw[2], (_Float16)cw[3] };
            *(half4*)(&Wt1[n * 584 + d_l * 36 + fg * 16 + kc * 4]) = h4;
        }
    }
#pragma unroll
    for (int li = 0; li < 4; ++li) {
        int l = w * 4 + li;
        half8 wf = *(const half8*)(&Wt0[l * 584 + n * 36 + kc * 8]);
        aO[li] = MFMA_F16(hf[li], wf, aO[li], 0, 0, 0);
    }
#pragma unroll
    for (int li = 0; li < 4; ++li) {
        half8 s8 = *(const half8*)(pS + li * 16384);
        half8 u8 = *(const half8*)(pU + li * 16384);
        hf[li] = s8 * u8;
    }
    LDS_BARRIER();
    // ---- tail consume(7): Wt1 ----
#pragma unroll
    for (int li = 0; li < 4; ++li) {
        int l = w * 4 + li;
        half8 wf = *(const half8*)(&Wt1[l * 584 + n * 36 + kc * 8]);
        aO[li] = MFMA_F16(hf[li], wf, aO[li], 0, 0, 0);
    }

#pragma unroll
    for (int dl = 0; dl < 4; ++dl) {
        float v = nsqD[dl];
        v += __shfl_xor(v, 16); v += __shfl_xor(v, 32);
        if (kc == 0)
            Np[(size_t)zh * 65536 + (size_t)(lg * 16 + n) * 512 + d0 + w * 4 + dl] = v;
    }
#pragma unroll
    for (int li = 0; li < 4; ++li) {
        int lgl = lg * 16 + w * 4 + li;
#pragma unroll
        for (int i = 0; i < 4; ++i)
            Rp[(size_t)zh * 1048576 +
               ((size_t)(kc * 4 + i) * 128 + lgl) * 512 + d0 + n] = aO[li][i];
    }
}

// ---------------------------------------------------------------------------
__global__ __launch_bounds__(128) void final_combine(
    const float* __restrict__ Rp, const float* __restrict__ Np,
    float* __restrict__ out)
{
    int rid = blockIdx.x;              // b*128 + l
    int l = rid & 127;
    int t = threadIdx.x;
    f32x4 r = { 0.f, 0.f, 0.f, 0.f };
    f32x4 nn = { 0.f, 0.f, 0.f, 0.f };
#pragma unroll
    for (int zh = 0; zh < 4; ++zh) {
        f32x4 rz = *(const f32x4*)(Rp + (size_t)zh * 1048576 + (size_t)rid * 512 + t * 4);
        f32x4 nz = *(const f32x4*)(Np + (size_t)zh * 65536 + (size_t)l * 512 + t * 4);
#pragma unroll
        for (int j = 0; j < 4; ++j) { r[j] += rz[j]; nn[j] += nz[j]; }
    }
    f32x4 y;
#pragma unroll
    for (int j = 0; j < 4; ++j) {
        float rr = 1.f / fmaxf(sqrtf(fmaxf(nn[j], 0.f)), 1e-12f);
        y[j] = r[j] * rr;
    }
    float s = y[0] * y[0] + y[1] * y[1] + y[2] * y[2] + y[3] * y[3];
#pragma unroll
    for (int off = 32; off > 0; off >>= 1) s += __shfl_down(s, off);
    __shared__ float sred[2];
    if ((t & 63) == 0) sred[t >> 6] = s;
    __syncthreads();
    float rr = 1.f / fmaxf(sqrtf(sred[0] + sred[1]), 1e-12f);
    f32x4 o = { y[0] * rr, y[1] * rr, y[2] * rr, y[3] * rr };
    *(f32x4*)(out + (size_t)rid * 512 + t * 4) = o;
}

// ===========================================================================
// SLOW FALLBACK (round-2 kernels, proven) — used when ws_size < WS_FAST
// ===========================================================================
__global__ __launch_bounds__(256) void up_kernel(
    const float* __restrict__ x,
    const float* __restrict__ wg, const float* __restrict__ wu,
    const float* __restrict__ tc1, const float* __restrict__ tc2,
    const float* __restrict__ usp, const float* __restrict__ vsp,
    _Float16* __restrict__ Hp)
{
    int lg = blockIdx.x >> 6;
    int f0 = (blockIdx.x & 63) * 16;
    int tid = threadIdx.x;
    int w = tid >> 6, lane = tid & 63;
    int n = lane & 15, kc = lane >> 4;

    __shared__ __align__(16) _Float16 Xt[256 * 40];
    __shared__ __align__(16) _Float16 Bh[32 * 16 * 24];
    __shared__ __align__(16) _Float16 Wt[16 * 528];
    __shared__ float CN[2 * 16 * 16];

    if (tid < 32) {
        int s = tid >> 4, ll = tid & 15;
        const float* row = (s ? tc2 : tc1) + (size_t)(lg * 16 + ll) * 16;
        float e[16], m = -1e30f, sum = 0.f;
#pragma unroll
        for (int k = 0; k < 16; ++k) m = fmaxf(m, row[k]);
#pragma unroll
        for (int k = 0; k < 16; ++k) { e[k] = __expf(row[k] - m); sum += e[k]; }
        float r = 1.f / sum;
#pragma unroll
        for (int k = 0; k < 16; ++k) CN[s * 256 + ll * 16 + k] = e[k] * r;
    }
    __syncthreads();

    half8 cf1 = { 0, 0, 0, 0, 0, 0, 0, 0 };
    half8 cf2 = { 0, 0, 0, 0, 0, 0, 0, 0 };
    if (kc < 2) {
#pragma unroll
        for (int j = 0; j < 8; ++j) {
            cf1[j] = (_Float16)CN[0 * 256 + n * 16 + kc * 8 + j];
            cf2[j] = (_Float16)CN[1 * 256 + n * 16 + kc * 8 + j];
        }
    }

    f32x4 zf = { 0.f, 0.f, 0.f, 0.f };
    f32x4 aU[4], aV[4];
#pragma unroll
    for (int i = 0; i < 4; ++i) { aU[i] = zf; aV[i] = zf; }
    float nsqU[4] = { 0.f, 0.f, 0.f, 0.f };
    float nsqV[4] = { 0.f, 0.f, 0.f, 0.f };

    for (int it = 0; it < 16; ++it) {
        int d0 = it * 32;
#pragma unroll
        for (int p = 0; p < 8; ++p) {
            int r = p * 32 + (tid >> 3);
            int fj = tid & 7;
            int ll = r >> 4, b = r & 15;
            f32x4 v = *(const f32x4*)(
                x + ((size_t)(b * 128 + lg * 16 + ll) * 512 + d0 + fj * 4));
            half4 h = { (_Float16)v[0], (_Float16)v[1],
                        (_Float16)v[2], (_Float16)v[3] };
            *(half4*)(&Xt[r * 40 + fj * 4]) = h;
        }
#pragma unroll
        for (int p = 0; p < 8; ++p) {
            int idx = p * 256 + tid;
            int q = idx & 3, dd = (idx >> 2) & 31, k = idx >> 7;
            f32x4 v = *(const f32x4*)(
                wg + ((size_t)k * 512 + d0 + dd) * 1024 + f0 + q * 4);
#pragma unroll
            for (int j = 0; j < 4; ++j)
                Bh[(dd * 16 + q * 4 + j) * 24 + k] = (_Float16)v[j];
        }
        __syncthreads();
#pragma unroll
        for (int fl = 0; fl < 4; ++fl) {
            int f_l = w * 4 + fl;
#pragma unroll
            for (int dg = 0; dg < 2; ++dg) {
                half8 a = { 0, 0, 0, 0, 0, 0, 0, 0 };
                if (kc < 2)
                    a = *(const half8*)(&Bh[((dg * 16 + n) * 16 + f_l) * 24 + kc * 8]);
                f32x4 cw = MFMA_F16(a, cf1, zf, 0, 0, 0);
                nsqU[fl] += cw[0] * cw[0] + cw[1] * cw[1]
                          + cw[2] * cw[2] + cw[3] * cw[3];
                half4 h4 = { (_Float16)cw[0], (_Float16)cw[1],
                             (_Float16)cw[2], (_Float16)cw[3] };
                *(half4*)(&Wt[n * 528 + f_l * 32 + dg * 16 + kc * 4]) = h4;
            }
        }
        __syncthreads();
#pragma unroll
        for (int li = 0; li < 4; ++li) {
            int l = w * 4 + li;
            half8 xf = *(const half8*)(&Xt[(l * 16 + n) * 40 + kc * 8]);
            half8 wf = *(const half8*)(&Wt[l * 528 + n * 32 + kc * 8]);
            aU[li] = MFMA_F16(xf, wf, aU[li], 0, 0, 0);
        }
#pragma unroll
        for (int p = 0; p < 8; ++p) {
            int idx = p * 256 + tid;
            int q = idx & 3, dd = (idx >> 2) & 31, k = idx >> 7;
            f32x4 v = *(const f32x4*)(
                wu + ((size_t)k * 512 + d0 + dd) * 1024 + f0 + q * 4);
#pragma unroll
            for (int j = 0; j < 4; ++j)
                Bh[(dd * 16 + q * 4 + j) * 24 + k] = (_Float16)v[j];
        }
        __syncthreads();
#pragma unroll
        for (int fl = 0; fl < 4; ++fl) {
            int f_l = w * 4 + fl;
#pragma unroll
            for (int dg = 0; dg < 2; ++dg) {
                half8 a = { 0, 0, 0, 0, 0, 0, 0, 0 };
                if (kc < 2)
                    a = *(const half8*)(&Bh[((dg * 16 + n) * 16 + f_l) * 24 + kc * 8]);
                f32x4 cw = MFMA_F16(a, cf2, zf, 0, 0, 0);
                nsqV[fl] += cw[0] * cw[0] + cw[1] * cw[1]
                          + cw[2] * cw[2] + cw[3] * cw[3];
                half4 h4 = { (_Float16)cw[0], (_Float16)cw[1],
                             (_Float16)cw[2], (_Float16)cw[3] };
                *(half4*)(&Wt[n * 528 + f_l * 32 + dg * 16 + kc * 4]) = h4;
            }
        }
        __syncthreads();
#pragma unroll
        for (int li = 0; li < 4; ++li) {
            int l = w * 4 + li;
            half8 xf = *(const half8*)(&Xt[(l * 16 + n) * 40 + kc * 8]);
            half8 wf = *(const half8*)(&Wt[l * 528 + n * 32 + kc * 8]);
            aV[li] = MFMA_F16(xf, wf, aV[li], 0, 0, 0);
        }
        __syncthreads();
    }

#pragma unroll
    for (int fl = 0; fl < 4; ++fl) {
        float vU = nsqU[fl], vV = nsqV[fl];
        vU += __shfl_xor(vU, 16); vU += __shfl_xor(vU, 32);
        vV += __shfl_xor(vV, 16); vV += __shfl_xor(vV, 32);
        if (kc == 0) {
            CN[0 * 256 + n * 16 + w * 4 + fl] = vU;
            CN[1 * 256 + n * 16 + w * 4 + fl] = vV;
        }
    }
    __syncthreads();

    int f = f0 + n;
    float usv = fabsf(usp[f]);
    float vsv = fabsf(vsp[f]) * 22.627416997969522f;
#pragma unroll
    for (int li = 0; li < 4; ++li) {
        int lgl = lg * 16 + w * 4 + li;
        float r1 = 1.f / fmaxf(sqrtf(CN[0 * 256 + (w * 4 + li) * 16 + n]), 1e-12f);
        float r2 = 1.f / fmaxf(sqrtf(CN[1 * 256 + (w * 4 + li) * 16 + n]), 1e-12f);
#pragma unroll
        for (int i = 0; i < 4; ++i) {
            float u = aU[li][i] * r1;
            float v = aV[li][i] * r2;
            float zz = vsv * v;
            float sil = zz / (1.f + __expf(-zz));
            float h = sil * (usv * u);
            Hp[((size_t)lgl * 16 + kc * 4 + i) * 1024 + f] = (_Float16)h;
        }
    }
}

__global__ __launch_bounds__(256) void down_kernel(
    const float* __restrict__ wd, const float* __restrict__ tc3,
    const _Float16* __restrict__ Hp, float* __restrict__ out)
{
    int lg = blockIdx.x >> 5;
    int d0 = (blockIdx.x & 31) * 16;
    int tid = threadIdx.x;
    int w = tid >> 6, lane = tid & 63;
    int n = lane & 15, kc = lane >> 4;

    __shared__ __align__(16) _Float16 Ht[256 * 40];
    __shared__ __align__(16) _Float16 Bh[32 * 16 * 24];
    __shared__ __align__(16) _Float16 Wt[16 * 528];
    __shared__ float CN[16 * 16];

    if (tid < 16) {
        const float* row = tc3 + (size_t)(lg * 16 + tid) * 16;
        float e[16], m = -1e30f, sum = 0.f;
#pragma unroll
        for (int k = 0; k < 16; ++k) m = fmaxf(m, row[k]);
#pragma unroll
        for (int k = 0; k < 16; ++k) { e[k] = __expf(row[k] - m); sum += e[k]; }
        float r = 1.f / sum;
#pragma unroll
        for (int k = 0; k < 16; ++k) CN[tid * 16 + k] = e[k] * r;
    }
    __syncthreads();

    half8 cf3 = { 0, 0, 0, 0, 0, 0, 0, 0 };
    if (kc < 2) {
#pragma unroll
        for (int j = 0; j < 8; ++j)
            cf3[j] = (_Float16)CN[n * 16 + kc * 8 + j];
    }

    f32x4 zf = { 0.f, 0.f, 0.f, 0.f };
    f32x4 aO[4];
#pragma unroll
    for (int i = 0; i < 4; ++i) aO[i] = zf;
    float nsqD[4] = { 0.f, 0.f, 0.f, 0.f };

    for (int it = 0; it < 32; ++it) {
        int f0 = it * 32;
#pragma unroll
        for (int p = 0; p < 8; ++p) {
            int r = p * 32 + (tid >> 3);
            int hj = tid & 7;
            int ll = r >> 4, b = r & 15;
            half4 v = *(const half4*)(
                Hp + ((size_t)(lg * 16 + ll) * 16 + b) * 1024 + f0 + hj * 4);
            *(half4*)(&Ht[r * 40 + hj * 4]) = v;
        }
#pragma unroll
        for (int p = 0; p < 8; ++p) {
            int idx = p * 256 + tid;
            int q = idx & 3, ff = (idx >> 2) & 31, k = idx >> 7;
            f32x4 v = *(const f32x4*)(
                wd + ((size_t)k * 1024 + f0 + ff) * 512 + d0 + q * 4);
#pragma unroll
            for (int j = 0; j < 4; ++j)
                Bh[(ff * 16 + q * 4 + j) * 24 + k] = (_Float16)v[j];
        }
        __syncthreads();
#pragma unroll
        for (int dl = 0; dl < 4; ++dl) {
            int d_l = w * 4 + dl;
#pragma unroll
            for (int fg = 0; fg < 2; ++fg) {
                half8 a = { 0, 0, 0, 0, 0, 0, 0, 0 };
                if (kc < 2)
                    a = *(const half8*)(&Bh[((fg * 16 + n) * 16 + d_l) * 24 + kc * 8]);
                f32x4 cw = MFMA_F16(a, cf3, zf, 0, 0, 0);
                nsqD[dl] += cw[0] * cw[0] + cw[1] * cw[1]
                          + cw[2] * cw[2] + cw[3] * cw[3];
                half4 h4 = { (_Float16)cw[0], (_Float16)cw[1],
                             (_Float16)cw[2], (_Float16)cw[3] };
                *(half4*)(&Wt[n * 528 + d_l * 32 + fg * 16 + kc * 4]) = h4;
            }
        }
        __syncthreads();
#pragma unroll
        for (int li = 0; li < 4; ++li) {
            int l = w * 4 + li;
            half8 hf = *(const half8*)(&Ht[(l * 16 + n) * 40 + kc * 8]);
            half8 wf = *(const half8*)(&Wt[l * 528 + n * 32 + kc * 8]);
            aO[li] = MFMA_F16(hf, wf, aO[li], 0, 0, 0);
        }
        __syncthreads();
    }

#pragma unroll
    for (int dl = 0; dl < 4; ++dl) {
        float v = nsqD[dl];
        v += __shfl_xor(v, 16); v += __shfl_xor(v, 32);
        if (kc == 0) CN[n * 16 + w * 4 + dl] = v;
    }
    __syncthreads();

#pragma unroll
    for (int li = 0; li < 4; ++li) {
        int lgl = lg * 16 + w * 4 + li;
        float r3 = 1.f / fmaxf(sqrtf(CN[(w * 4 + li) * 16 + n]), 1e-12f);
#pragma unroll
        for (int i = 0; i < 4; ++i)
            out[((size_t)(kc * 4 + i) * 128 + lgl) * 512 + d0 + n] = aO[li][i] * r3;
    }
}

__global__ __launch_bounds__(128) void final_kernel(float* __restrict__ out)
{
    int rid = blockIdx.x;
    int t = threadIdx.x;
    f32x4 y = *(const f32x4*)(out + (size_t)rid * 512 + t * 4);
    float s = y[0] * y[0] + y[1] * y[1] + y[2] * y[2] + y[3] * y[3];
#pragma unroll
    for (int off = 32; off > 0; off >>= 1) s += __shfl_down(s, off);
    __shared__ float sred[2];
    if ((t & 63) == 0) sred[t >> 6] = s;
    __syncthreads();
    float rr = 1.f / fmaxf(sqrtf(sred[0] + sred[1]), 1e-12f);
    f32x4 o = { y[0] * rr, y[1] * rr, y[2] * rr, y[3] * rr };
    *(f32x4*)(out + (size_t)rid * 512 + t * 4) = o;
}

// ---------------------------------------------------------------------------
extern "C" void kernel_launch(void* const* d_in, const int* in_sizes, int n_in,
                              void* d_out, int out_size, void* d_ws, size_t ws_size,
                              hipStream_t stream)
{
    (void)in_sizes; (void)n_in; (void)out_size;
    const float* x   = (const float*)d_in[0];
    const float* wg  = (const float*)d_in[1];
    const float* wu  = (const float*)d_in[2];
    const float* wd  = (const float*)d_in[3];
    const float* tc1 = (const float*)d_in[4];
    const float* tc2 = (const float*)d_in[5];
    const float* tc3 = (const float*)d_in[6];
    const float* usp = (const float*)d_in[7];
    const float* vsp = (const float*)d_in[8];
    float* outp = (float*)d_out;
    char* ws = (char*)d_ws;

    if (ws_size >= WS_FAST) {
        _Float16* P1  = (_Float16*)(ws + OFF_P1);
        _Float16* P2  = (_Float16*)(ws + OFF_P2);
        _Float16* P3n = (_Float16*)(ws + OFF_P3n);  // 17..33 MiB (after Np)
        _Float16* XA  = (_Float16*)(ws + OFF_XA);   // 32..34 MiB
        _Float16* U2  = (_Float16*)(ws + OFF_U2);   // 34..38 MiB
        _Float16* S   = (_Float16*)(ws + OFF_S);    // 38..42 MiB
        float* Rp = (float*)(ws + OFF_P1);   // overlays P1 (dead after up)
        float* Np = (float*)(ws + OFF_P2);   // 16..17 MiB (P2 dead after up)
        prep_basis_all<<<dim3(512, 2), dim3(256), 0, stream>>>(
            wg, wu, wd, P1, P2, P3n, 0);                   // P1, P2
        prep_x<<<dim3(256), dim3(256), 0, stream>>>(x, XA);
        up_split<<<dim3(1024), dim3(256), 0, stream>>>(P1, P2, XA, tc1, tc2,
                                                       usp, vsp, U2, S);
        prep_basis_all<<<dim3(512, 1), dim3(256), 0, stream>>>(
            wg, wu, wd, P1, P2, P3n, 2);                   // P3 at 17 MiB
        down_fast<<<dim3(1024), dim3(256), 0, stream>>>(P3n, tc3, S, U2, Rp, Np);
        final_combine<<<dim3(2048), dim3(128), 0, stream>>>(Rp, Np, outp);
    } else {
        _Float16* Hp = (_Float16*)ws;
        up_kernel<<<dim3(512), dim3(256), 0, stream>>>(x, wg, wu, tc1, tc2,
                                                       usp, vsp, Hp);
        down_kernel<<<dim3(256), dim3(256), 0, stream>>>(wd, tc3, Hp, outp);
        final_kernel<<<dim3(2048), dim3(128), 0, stream>>>(outp);
    }
}

// Round 9
// 239.741 us; speedup vs baseline: 1.0303x; 1.0303x over previous
//
#include <hip/hip_runtime.h>
#include <hip/hip_bf16.h>
#include <cmath>

// ---------------------------------------------------------------------------
// NPerTokenSwishGLU_Basis — fused f16-MFMA implementation (gfx950), round 16.
//
// R15 post-mortem: E/O distance-2 spilled ((256,4) empirically pins VGPR=64;
// WRITE 8->40MB). Reverted. Cross-round accounting: every up variant since
// R7 moves ~512MB of L2-side reads at a constant ~9-10.5 TB/s aggregate —
// time tracks BYTES, not schedule (why occupancy/barrier/unroll/pipeline
// rounds were all null). R16 reduces bytes: 8-wave (512-thr) blocks that
// double the output tile with unchanged per-wave register footprint:
//  - up: 32 f-rows/block (mix: wave w = f-rows w*4..; consume: wave w =
//    l-rows (w&3)*4.., f-half w>>2) -> XA re-reads halve (-128MB).
//  - down: 32 d-rows/block -> S/U2 re-reads halve (-128MB).
// LDS 76.8KB -> 2 blocks/CU, still 16 waves/CU. __launch_bounds__(512,2)
// (R9-proven >=96 VGPR grant, demand ~60).
// ---------------------------------------------------------------------------

typedef _Float16 half8 __attribute__((ext_vector_type(8)));
typedef _Float16 half4 __attribute__((ext_vector_type(4)));
typedef float    f32x4 __attribute__((ext_vector_type(4)));
typedef float    f32x2 __attribute__((ext_vector_type(2)));

#define MFMA_F16  __builtin_amdgcn_mfma_f32_16x16x32_f16
#define MFMA16    __builtin_amdgcn_mfma_f32_16x16x16f16

// LDS-only barrier: drain DS ops, leave global loads in flight.
#define LDS_BARRIER()                                           \
    do {                                                        \
        asm volatile("s_waitcnt lgkmcnt(0)" ::: "memory");      \
        __builtin_amdgcn_s_barrier();                           \
    } while (0)

static constexpr size_t OFF_P1  = 0;            // 16 MiB; Rp overlay (down)
static constexpr size_t OFF_P2  = 16777216;     // 16 MiB; Np overlay (down, 1 MiB)
static constexpr size_t OFF_P3n = 17825792;     // 16 MiB at 17 MiB (after Np)
static constexpr size_t OFF_XA  = 33554432;     // 2 MiB at 32 MiB
static constexpr size_t OFF_U2  = 35651584;     // 4 MiB at 34 MiB
static constexpr size_t OFF_S   = 39845888;     // 4 MiB at 38 MiB (top 42 MiB)
static constexpr size_t WS_FAST = 54525952;     // 52 MiB (proven)

// ---------------------------------------------------------------------------
// prep (two-sided coalesced transpose), 32x32 tiles (R13):
//   z=0,1: wg/wu (K,512,1024)=[k][d][f] -> P[f][d][k]
//   z=2  : wd    (K,1024,512)=[k][f][d] -> P3[d][f][k]
// ---------------------------------------------------------------------------
__global__ __launch_bounds__(256) void prep_basis_all(
    const float* __restrict__ wg, const float* __restrict__ wu,
    const float* __restrict__ wd,
    _Float16* __restrict__ P1, _Float16* __restrict__ P2,
    _Float16* __restrict__ P3, int zoff)
{
    int z = blockIdx.y + zoff;
    const float* src = (z == 0) ? wg : (z == 1) ? wu : wd;
    _Float16*    dst = (z == 0) ? P1 : (z == 1) ? P2 : P3;
    int Amin = (z == 2) ? 1024 : 512;    // minor-dim size
    int Bmaj = (z == 2) ? 512 : 1024;    // major-dim size
    int nM = Bmaj >> 5;
    int m0 = (blockIdx.x / nM) * 32;     // minor base
    int M0 = (blockIdx.x % nM) * 32;     // major base

    __shared__ float S[16 * 1088];       // [k][row*34 + col]
    int t = threadIdx.x;

    int row = t >> 3;                    // 0..31 (minor row)
    int cg  = t & 7;                     // 0..7 (16B col group)
#pragma unroll
    for (int k = 0; k < 16; ++k) {
        f32x4 v = *(const f32x4*)(
            src + (size_t)k * Amin * Bmaj + (size_t)(m0 + row) * Bmaj + M0 + cg * 4);
        f32x2 lo = { v[0], v[1] };
        f32x2 hi = { v[2], v[3] };
        *(f32x2*)(&S[k * 1088 + row * 34 + cg * 4])     = lo;
        *(f32x2*)(&S[k * 1088 + row * 34 + cg * 4 + 2]) = hi;
    }
    __syncthreads();

    int mn = t & 31, mjq = t >> 5;
#pragma unroll
    for (int q = 0; q < 4; ++q) {
        int mj = q * 8 + mjq;
        half8 v0, v1;
#pragma unroll
        for (int k = 0; k < 8; ++k) v0[k] = (_Float16)S[k * 1088 + mn * 34 + mj];
#pragma unroll
        for (int k = 0; k < 8; ++k) v1[k] = (_Float16)S[(k + 8) * 1088 + mn * 34 + mj];
        _Float16* out = dst + ((size_t)(M0 + mj) * Amin + m0 + mn) * 16;
        *(half8*)out       = v0;
        *(half8*)(out + 8) = v1;
    }
}

// ---------------------------------------------------------------------------
// prep_x: x fp32 [b][l][d] -> XA f16 [l][d>>3][b][8]
// grid 256 = 128 l x 2 b-halves, 256 threads.
// ---------------------------------------------------------------------------
__global__ __launch_bounds__(256) void prep_x(
    const float* __restrict__ x, _Float16* __restrict__ XA)
{
    int l = blockIdx.x >> 1, bh = blockIdx.x & 1;
    __shared__ __align__(16) _Float16 XT[8][524];
    int t = threadIdx.x;

    int bl = t >> 5, q = t & 31;          // b-local 0..7, q 0..31
    int b = bh * 8 + bl;
#pragma unroll
    for (int j = 0; j < 4; ++j) {
        f32x4 v = *(const f32x4*)(x + ((size_t)(b * 128 + l) * 512 + j * 128 + q * 4));
#pragma unroll
        for (int i = 0; i < 4; ++i)
            XT[bl][j * 128 + q * 4 + i] = (_Float16)v[i];
    }
    __syncthreads();

    int c = t >> 2, bi = t & 3;           // c 0..63
#pragma unroll
    for (int s = 0; s < 2; ++s) {
        int blw = bi * 2 + s;             // 0..7
        half8 h = *(const half8*)(&XT[blw][c * 8]);
        *(half8*)(XA + (((size_t)(l * 64 + c) * 16 + bh * 8 + blw) * 8)) = h;
    }
}

// ---------------------------------------------------------------------------
// up_split (R16): 512 blocks = mh(2) x 8 lg x 32 f-tiles(32-wide), 512 thr.
// Mix: wave w owns f-rows w*4..w*4+3 (8 waves x 4 = 32 f).
// Consume: wave w owns l-rows (w&3)*4.. and f-half (w>>2).
// LDS: Wt[2][16*1168] = 74752 B + CN 2048 B -> 2 blocks/CU (16 waves).
// ---------------------------------------------------------------------------
__global__ __launch_bounds__(512, 2) void up_split(
    const _Float16* __restrict__ P1, const _Float16* __restrict__ P2,
    const _Float16* __restrict__ XA,
    const float* __restrict__ tc1, const float* __restrict__ tc2,
    const float* __restrict__ usp, const float* __restrict__ vsp,
    _Float16* __restrict__ U2, _Float16* __restrict__ S)
{
    int bid = blockIdx.x;
    int mh = bid >> 8;                  // 0: gate/u, 1: up/v
    int lg = (bid >> 5) & 7;
    int f0 = (bid & 31) * 32;
    int tid = threadIdx.x;
    int wq = tid >> 6;                  // 0..7
    int lane = tid & 63;
    int n = lane & 15, kc = lane >> 4;
    int lh = wq & 3;                    // consume l-group
    int fh = wq >> 2;                   // consume f-half

    const _Float16* P  = mh ? P2 : P1;
    const float*    tc = mh ? tc2 : tc1;

    __shared__ __align__(16) _Float16 Wt[2][16 * 1168]; // [buf][l*1168+f*36+d]
    __shared__ float CN[512];           // softmax (256) then nsq [l][f 0..31]
    _Float16* Wt0 = &Wt[0][0];
    _Float16* Wt1 = &Wt[1][0];

    // element-unit base pointers (advance +512 per 32-d chunk)
    const _Float16* pP  = P + ((size_t)(f0 + wq * 4) * 512 + n) * 16 + kc * 4;
    const _Float16* pXA = XA + (((size_t)(lg * 16 + lh * 4) * 64 + kc) * 16 + n) * 8;

    half4 pa[4][2];
    // ---- prologue: issue pa(0); softmax + barrier cover the latency ----
#pragma unroll
    for (int fl = 0; fl < 4; ++fl)
#pragma unroll
        for (int dg = 0; dg < 2; ++dg)
            pa[fl][dg] = *(const half4*)(pP + fl * 8192 + dg * 256);
    const _Float16* qP = pP + 512;

    if (tid < 16) {
        const float* row = tc + (size_t)(lg * 16 + tid) * 16;
        float e[16], m = -1e30f, sum = 0.f;
#pragma unroll
        for (int k = 0; k < 16; ++k) m = fmaxf(m, row[k]);
#pragma unroll
        for (int k = 0; k < 16; ++k) { e[k] = __expf(row[k] - m); sum += e[k]; }
        float r = 1.f / sum;
#pragma unroll
        for (int k = 0; k < 16; ++k) CN[tid * 16 + k] = e[k] * r;
    }
    __syncthreads();

    half4 cf;
#pragma unroll
    for (int j = 0; j < 4; ++j)
        cf[j] = (_Float16)CN[n * 16 + kc * 4 + j];
    __syncthreads();                    // CN about to be reused for nsq

    f32x4 zf = { 0.f, 0.f, 0.f, 0.f };
    f32x4 aU[4];
#pragma unroll
    for (int i = 0; i < 4; ++i) aU[i] = zf;
    float nsq[4] = { 0.f, 0.f, 0.f, 0.f };
    half8 xf[4];

#pragma unroll 1
    for (int it = 0; it < 16; ++it) {
        _Float16* WtW = (it & 1) ? Wt1 : Wt0;
        const _Float16* WtR = (it & 1) ? Wt0 : Wt1;

        // ---- mix(it): wave's 4 f-rows, K=16 MFMA ----
#pragma unroll
        for (int fl = 0; fl < 4; ++fl) {
            int f_l = wq * 4 + fl;
#pragma unroll
            for (int dg = 0; dg < 2; ++dg) {
                f32x4 c1 = MFMA16(pa[fl][dg], cf, zf, 0, 0, 0);
                nsq[fl] += c1[0] * c1[0] + c1[1] * c1[1]
                         + c1[2] * c1[2] + c1[3] * c1[3];
                half4 h1 = { (_Float16)c1[0], (_Float16)c1[1],
                             (_Float16)c1[2], (_Float16)c1[3] };
                *(half4*)(&WtW[n * 1168 + f_l * 36 + dg * 16 + kc * 4]) = h1;
            }
        }
        // ---- issue pa(it+1) into freed regs ----
        if (it < 15) {
#pragma unroll
            for (int fl = 0; fl < 4; ++fl)
#pragma unroll
                for (int dg = 0; dg < 2; ++dg)
                    pa[fl][dg] = *(const half4*)(qP + fl * 8192 + dg * 256);
        }
        // ---- consume(it-1): wave's l-group x f-half ----
        if (it > 0) {
#pragma unroll
            for (int li = 0; li < 4; ++li) {
                int l = lh * 4 + li;
                half8 wU = *(const half8*)(
                    &WtR[l * 1168 + (fh * 16 + n) * 36 + kc * 8]);
                aU[li] = MFMA_F16(xf[li], wU, aU[li], 0, 0, 0);
            }
        }
        // ---- load xf(it): 1KB dense per wave ----
#pragma unroll
        for (int li = 0; li < 4; ++li)
            xf[li] = *(const half8*)(pXA + li * 8192);
        pXA += 512;
        qP += 512;
        LDS_BARRIER();
    }
    // ---- tail consume (chunk 15, buffer 1) ----
#pragma unroll
    for (int li = 0; li < 4; ++li) {
        int l = lh * 4 + li;
        half8 wU = *(const half8*)(
            &Wt1[l * 1168 + (fh * 16 + n) * 36 + kc * 8]);
        aU[li] = MFMA_F16(xf[li], wU, aU[li], 0, 0, 0);
    }

    // ---- norm reduce: nsq[fl] is (l=n, f=wq*4+fl) summed over lane d ----
#pragma unroll
    for (int fl = 0; fl < 4; ++fl) {
        float vU = nsq[fl];
        vU += __shfl_xor(vU, 16); vU += __shfl_xor(vU, 32);
        if (kc == 0) CN[n * 32 + wq * 4 + fl] = vU;
    }
    __syncthreads();

    int f = f0 + fh * 16 + n;
    float sc = mh ? (fabsf(vsp[f]) * 22.627416997969522f)   // vs = |vsp|*sqrt(512)
                  : fabsf(usp[f]);                          // us = |usp|
    _Float16* Out = mh ? S : U2;
#pragma unroll
    for (int li = 0; li < 4; ++li) {
        int ll = lh * 4 + li;
        int lgl = lg * 16 + ll;
        float r1 = 1.f / fmaxf(sqrtf(CN[ll * 32 + fh * 16 + n]), 1e-12f);
#pragma unroll
        for (int i = 0; i < 4; ++i) {
            float val = aU[li][i] * r1 * sc;       // us*u'  or  vs*v'
            if (mh) val = val / (1.f + __expf(-val));   // silu(vs*v')
            // layout [l][f>>3][b][8]
            Out[(((size_t)lgl * 128 + (f >> 3)) * 16 + kc * 4 + i) * 8 + (f & 7)] =
                (_Float16)val;
        }
    }
}

// ---------------------------------------------------------------------------
// down_fast (R16): 512 blocks = 4 zh x 8 lg x 16 d-tiles(32-wide), 512 thr.
// Mix: wave w owns d-rows w*4..; consume: l-group (w&3), d-half (w>>2).
// LDS: Wt[2][16*1168] + CN 2048 -> 2 blocks/CU.
// ---------------------------------------------------------------------------
__global__ __launch_bounds__(512, 2) void down_fast(
    const _Float16* __restrict__ P3, const float* __restrict__ tc3,
    const _Float16* __restrict__ S, const _Float16* __restrict__ U2,
    float* __restrict__ Rp, float* __restrict__ Np)
{
    int bid = blockIdx.x;
    int zh = bid >> 7;                  // 0..3
    int lg = (bid >> 4) & 7;
    int d0 = (bid & 15) * 32;
    int tid = threadIdx.x;
    int wq = tid >> 6;                  // 0..7
    int lane = tid & 63;
    int n = lane & 15, kc = lane >> 4;
    int lh = wq & 3;                    // consume l-group
    int dh = wq >> 2;                   // consume d-half

    __shared__ __align__(16) _Float16 Wt[2][16 * 1168]; // [buf][l*1168+d*36+f]
    __shared__ float CN[512];
    _Float16* Wt0 = &Wt[0][0];
    _Float16* Wt1 = &Wt[1][0];

    // element-unit base pointers (advance +512 per 32-f chunk)
    const _Float16* pP3 = P3 + ((size_t)(d0 + wq * 4) * 1024 + zh * 256 + n) * 16 + kc * 4;
    size_t hoff = (((size_t)(lg * 16 + lh * 4) * 128 + zh * 32 + kc) * 16 + n) * 8;
    const _Float16* pS = S + hoff;
    const _Float16* pU = U2 + hoff;

    half4 pa[4][2];
    // ---- prologue: issue pa(0) ----
#pragma unroll
    for (int dl = 0; dl < 4; ++dl)
#pragma unroll
        for (int fg = 0; fg < 2; ++fg)
            pa[dl][fg] = *(const half4*)(pP3 + dl * 16384 + fg * 256);
    const _Float16* qP3 = pP3 + 512;

    if (tid < 16) {
        const float* row = tc3 + (size_t)(lg * 16 + tid) * 16;
        float e[16], m = -1e30f, sum = 0.f;
#pragma unroll
        for (int k = 0; k < 16; ++k) m = fmaxf(m, row[k]);
#pragma unroll
        for (int k = 0; k < 16; ++k) { e[k] = __expf(row[k] - m); sum += e[k]; }
        float r = 1.f / sum;
#pragma unroll
        for (int k = 0; k < 16; ++k) CN[tid * 16 + k] = e[k] * r;
    }
    __syncthreads();

    half4 cf3;
#pragma unroll
    for (int j = 0; j < 4; ++j)
        cf3[j] = (_Float16)CN[n * 16 + kc * 4 + j];
    __syncthreads();                    // CN about to be reused for nsq

    f32x4 zf = { 0.f, 0.f, 0.f, 0.f };
    f32x4 aO[4];
#pragma unroll
    for (int i = 0; i < 4; ++i) aO[i] = zf;
    float nsqD[4] = { 0.f, 0.f, 0.f, 0.f };
    half8 hf[4];

#pragma unroll 1
    for (int it = 0; it < 8; ++it) {
        _Float16* WtW = (it & 1) ? Wt1 : Wt0;
        const _Float16* WtR = (it & 1) ? Wt0 : Wt1;

        // ---- mix(it): wave's 4 d-rows, K=16 MFMA ----
#pragma unroll
        for (int dl = 0; dl < 4; ++dl) {
            int d_l = wq * 4 + dl;
#pragma unroll
            for (int fg = 0; fg < 2; ++fg) {
                f32x4 cw = MFMA16(pa[dl][fg], cf3, zf, 0, 0, 0);
                nsqD[dl] += cw[0] * cw[0] + cw[1] * cw[1]
                          + cw[2] * cw[2] + cw[3] * cw[3];
                half4 h4 = { (_Float16)cw[0], (_Float16)cw[1],
                             (_Float16)cw[2], (_Float16)cw[3] };
                *(half4*)(&WtW[n * 1168 + d_l * 36 + fg * 16 + kc * 4]) = h4;
            }
        }
        // ---- issue pa(it+1) ----
        if (it < 7) {
#pragma unroll
            for (int dl = 0; dl < 4; ++dl)
#pragma unroll
                for (int fg = 0; fg < 2; ++fg)
                    pa[dl][fg] = *(const half4*)(qP3 + dl * 16384 + fg * 256);
        }
        // ---- consume(it-1): wave's l-group x d-half ----
        if (it > 0) {
#pragma unroll
            for (int li = 0; li < 4; ++li) {
                int l = lh * 4 + li;
                half8 wf = *(const half8*)(
                    &WtR[l * 1168 + (dh * 16 + n) * 36 + kc * 8]);
                aO[li] = MFMA_F16(hf[li], wf, aO[li], 0, 0, 0);
            }
        }
        // ---- load hf(it) = S * U2 (each 1KB dense per wave) ----
#pragma unroll
        for (int li = 0; li < 4; ++li) {
            half8 s8 = *(const half8*)(pS + li * 16384);
            half8 u8 = *(const half8*)(pU + li * 16384);
            hf[li] = s8 * u8;
        }
        pS += 512;
        pU += 512;
        qP3 += 512;
        LDS_BARRIER();
    }
    // ---- tail consume (chunk 7, buffer 1) ----
#pragma unroll
    for (int li = 0; li < 4; ++li) {
        int l = lh * 4 + li;
        half8 wf = *(const half8*)(
            &Wt1[l * 1168 + (dh * 16 + n) * 36 + kc * 8]);
        aO[li] = MFMA_F16(hf[li], wf, aO[li], 0, 0, 0);
    }

    // ---- norm partials: nsqD[dl] is (l=n, d=wq*4+dl) ----
#pragma unroll
    for (int dl = 0; dl < 4; ++dl) {
        float v = nsqD[dl];
        v += __shfl_xor(v, 16); v += __shfl_xor(v, 32);
        if (kc == 0)
            Np[(size_t)zh * 65536 + (size_t)(lg * 16 + n) * 512 + d0 + wq * 4 + dl] = v;
    }
#pragma unroll
    for (int li = 0; li < 4; ++li) {
        int lgl = lg * 16 + lh * 4 + li;
#pragma unroll
        for (int i = 0; i < 4; ++i)
            Rp[(size_t)zh * 1048576 +
               ((size_t)(kc * 4 + i) * 128 + lgl) * 512 + d0 + dh * 16 + n] = aO[li][i];
    }
}

// ---------------------------------------------------------------------------
__global__ __launch_bounds__(128) void final_combine(
    const float* __restrict__ Rp, const float* __restrict__ Np,
    float* __restrict__ out)
{
    int rid = blockIdx.x;              // b*128 + l
    int l = rid & 127;
    int t = threadIdx.x;
    f32x4 r = { 0.f, 0.f, 0.f, 0.f };
    f32x4 nn = { 0.f, 0.f, 0.f, 0.f };
#pragma unroll
    for (int zh = 0; zh < 4; ++zh) {
        f32x4 rz = *(const f32x4*)(Rp + (size_t)zh * 1048576 + (size_t)rid * 512 + t * 4);
        f32x4 nz = *(const f32x4*)(Np + (size_t)zh * 65536 + (size_t)l * 512 + t * 4);
#pragma unroll
        for (int j = 0; j < 4; ++j) { r[j] += rz[j]; nn[j] += nz[j]; }
    }
    f32x4 y;
#pragma unroll
    for (int j = 0; j < 4; ++j) {
        float rr = 1.f / fmaxf(sqrtf(fmaxf(nn[j], 0.f)), 1e-12f);
        y[j] = r[j] * rr;
    }
    float s = y[0] * y[0] + y[1] * y[1] + y[2] * y[2] + y[3] * y[3];
#pragma unroll
    for (int off = 32; off > 0; off >>= 1) s += __shfl_down(s, off);
    __shared__ float sred[2];
    if ((t & 63) == 0) sred[t >> 6] = s;
    __syncthreads();
    float rr = 1.f / fmaxf(sqrtf(sred[0] + sred[1]), 1e-12f);
    f32x4 o = { y[0] * rr, y[1] * rr, y[2] * rr, y[3] * rr };
    *(f32x4*)(out + (size_t)rid * 512 + t * 4) = o;
}

// ===========================================================================
// SLOW FALLBACK (round-2 kernels, proven) — used when ws_size < WS_FAST
// ===========================================================================
__global__ __launch_bounds__(256) void up_kernel(
    const float* __restrict__ x,
    const float* __restrict__ wg, const float* __restrict__ wu,
    const float* __restrict__ tc1, const float* __restrict__ tc2,
    const float* __restrict__ usp, const float* __restrict__ vsp,
    _Float16* __restrict__ Hp)
{
    int lg = blockIdx.x >> 6;
    int f0 = (blockIdx.x & 63) * 16;
    int tid = threadIdx.x;
    int w = tid >> 6, lane = tid & 63;
    int n = lane & 15, kc = lane >> 4;

    __shared__ __align__(16) _Float16 Xt[256 * 40];
    __shared__ __align__(16) _Float16 Bh[32 * 16 * 24];
    __shared__ __align__(16) _Float16 Wt[16 * 528];
    __shared__ float CN[2 * 16 * 16];

    if (tid < 32) {
        int s = tid >> 4, ll = tid & 15;
        const float* row = (s ? tc2 : tc1) + (size_t)(lg * 16 + ll) * 16;
        float e[16], m = -1e30f, sum = 0.f;
#pragma unroll
        for (int k = 0; k < 16; ++k) m = fmaxf(m, row[k]);
#pragma unroll
        for (int k = 0; k < 16; ++k) { e[k] = __expf(row[k] - m); sum += e[k]; }
        float r = 1.f / sum;
#pragma unroll
        for (int k = 0; k < 16; ++k) CN[s * 256 + ll * 16 + k] = e[k] * r;
    }
    __syncthreads();

    half8 cf1 = { 0, 0, 0, 0, 0, 0, 0, 0 };
    half8 cf2 = { 0, 0, 0, 0, 0, 0, 0, 0 };
    if (kc < 2) {
#pragma unroll
        for (int j = 0; j < 8; ++j) {
            cf1[j] = (_Float16)CN[0 * 256 + n * 16 + kc * 8 + j];
            cf2[j] = (_Float16)CN[1 * 256 + n * 16 + kc * 8 + j];
        }
    }

    f32x4 zf = { 0.f, 0.f, 0.f, 0.f };
    f32x4 aU[4], aV[4];
#pragma unroll
    for (int i = 0; i < 4; ++i) { aU[i] = zf; aV[i] = zf; }
    float nsqU[4] = { 0.f, 0.f, 0.f, 0.f };
    float nsqV[4] = { 0.f, 0.f, 0.f, 0.f };

    for (int it = 0; it < 16; ++it) {
        int d0 = it * 32;
#pragma unroll
        for (int p = 0; p < 8; ++p) {
            int r = p * 32 + (tid >> 3);
            int fj = tid & 7;
            int ll = r >> 4, b = r & 15;
            f32x4 v = *(const f32x4*)(
                x + ((size_t)(b * 128 + lg * 16 + ll) * 512 + d0 + fj * 4));
            half4 h = { (_Float16)v[0], (_Float16)v[1],
                        (_Float16)v[2], (_Float16)v[3] };
            *(half4*)(&Xt[r * 40 + fj * 4]) = h;
        }
#pragma unroll
        for (int p = 0; p < 8; ++p) {
            int idx = p * 256 + tid;
            int q = idx & 3, dd = (idx >> 2) & 31, k = idx >> 7;
            f32x4 v = *(const f32x4*)(
                wg + ((size_t)k * 512 + d0 + dd) * 1024 + f0 + q * 4);
#pragma unroll
            for (int j = 0; j < 4; ++j)
                Bh[(dd * 16 + q * 4 + j) * 24 + k] = (_Float16)v[j];
        }
        __syncthreads();
#pragma unroll
        for (int fl = 0; fl < 4; ++fl) {
            int f_l = w * 4 + fl;
#pragma unroll
            for (int dg = 0; dg < 2; ++dg) {
                half8 a = { 0, 0, 0, 0, 0, 0, 0, 0 };
                if (kc < 2)
                    a = *(const half8*)(&Bh[((dg * 16 + n) * 16 + f_l) * 24 + kc * 8]);
                f32x4 cw = MFMA_F16(a, cf1, zf, 0, 0, 0);
                nsqU[fl] += cw[0] * cw[0] + cw[1] * cw[1]
                          + cw[2] * cw[2] + cw[3] * cw[3];
                half4 h4 = { (_Float16)cw[0], (_Float16)cw[1],
                             (_Float16)cw[2], (_Float16)cw[3] };
                *(half4*)(&Wt[n * 528 + f_l * 32 + dg * 16 + kc * 4]) = h4;
            }
        }
        __syncthreads();
#pragma unroll
        for (int li = 0; li < 4; ++li) {
            int l = w * 4 + li;
            half8 xf = *(const half8*)(&Xt[(l * 16 + n) * 40 + kc * 8]);
            half8 wf = *(const half8*)(&Wt[l * 528 + n * 32 + kc * 8]);
            aU[li] = MFMA_F16(xf, wf, aU[li], 0, 0, 0);
        }
#pragma unroll
        for (int p = 0; p < 8; ++p) {
            int idx = p * 256 + tid;
            int q = idx & 3, dd = (idx >> 2) & 31, k = idx >> 7;
            f32x4 v = *(const f32x4*)(
                wu + ((size_t)k * 512 + d0 + dd) * 1024 + f0 + q * 4);
#pragma unroll
            for (int j = 0; j < 4; ++j)
                Bh[(dd * 16 + q * 4 + j) * 24 + k] = (_Float16)v[j];
        }
        __syncthreads();
#pragma unroll
        for (int fl = 0; fl < 4; ++fl) {
            int f_l = w * 4 + fl;
#pragma unroll
            for (int dg = 0; dg < 2; ++dg) {
                half8 a = { 0, 0, 0, 0, 0, 0, 0, 0 };
                if (kc < 2)
                    a = *(const half8*)(&Bh[((dg * 16 + n) * 16 + f_l) * 24 + kc * 8]);
                f32x4 cw = MFMA_F16(a, cf2, zf, 0, 0, 0);
                nsqV[fl] += cw[0] * cw[0] + cw[1] * cw[1]
                          + cw[2] * cw[2] + cw[3] * cw[3];
                half4 h4 = { (_Float16)cw[0], (_Float16)cw[1],
                             (_Float16)cw[2], (_Float16)cw[3] };
                *(half4*)(&Wt[n * 528 + f_l * 32 + dg * 16 + kc * 4]) = h4;
            }
        }
        __syncthreads();
#pragma unroll
        for (int li = 0; li < 4; ++li) {
            int l = w * 4 + li;
            half8 xf = *(const half8*)(&Xt[(l * 16 + n) * 40 + kc * 8]);
            half8 wf = *(const half8*)(&Wt[l * 528 + n * 32 + kc * 8]);
            aV[li] = MFMA_F16(xf, wf, aV[li], 0, 0, 0);
        }
        __syncthreads();
    }

#pragma unroll
    for (int fl = 0; fl < 4; ++fl) {
        float vU = nsqU[fl], vV = nsqV[fl];
        vU += __shfl_xor(vU, 16); vU += __shfl_xor(vU, 32);
        vV += __shfl_xor(vV, 16); vV += __shfl_xor(vV, 32);
        if (kc == 0) {
            CN[0 * 256 + n * 16 + w * 4 + fl] = vU;
            CN[1 * 256 + n * 16 + w * 4 + fl] = vV;
        }
    }
    __syncthreads();

    int f = f0 + n;
    float usv = fabsf(usp[f]);
    float vsv = fabsf(vsp[f]) * 22.627416997969522f;
#pragma unroll
    for (int li = 0; li < 4; ++li) {
        int lgl = lg * 16 + w * 4 + li;
        float r1 = 1.f / fmaxf(sqrtf(CN[0 * 256 + (w * 4 + li) * 16 + n]), 1e-12f);
        float r2 = 1.f / fmaxf(sqrtf(CN[1 * 256 + (w * 4 + li) * 16 + n]), 1e-12f);
#pragma unroll
        for (int i = 0; i < 4; ++i) {
            float u = aU[li][i] * r1;
            float v = aV[li][i] * r2;
            float zz = vsv * v;
            float sil = zz / (1.f + __expf(-zz));
            float h = sil * (usv * u);
            Hp[((size_t)lgl * 16 + kc * 4 + i) * 1024 + f] = (_Float16)h;
        }
    }
}

__global__ __launch_bounds__(256) void down_kernel(
    const float* __restrict__ wd, const float* __restrict__ tc3,
    const _Float16* __restrict__ Hp, float* __restrict__ out)
{
    int lg = blockIdx.x >> 5;
    int d0 = (blockIdx.x & 31) * 16;
    int tid = threadIdx.x;
    int w = tid >> 6, lane = tid & 63;
    int n = lane & 15, kc = lane >> 4;

    __shared__ __align__(16) _Float16 Ht[256 * 40];
    __shared__ __align__(16) _Float16 Bh[32 * 16 * 24];
    __shared__ __align__(16) _Float16 Wt[16 * 528];
    __shared__ float CN[16 * 16];

    if (tid < 16) {
        const float* row = tc3 + (size_t)(lg * 16 + tid) * 16;
        float e[16], m = -1e30f, sum = 0.f;
#pragma unroll
        for (int k = 0; k < 16; ++k) m = fmaxf(m, row[k]);
#pragma unroll
        for (int k = 0; k < 16; ++k) { e[k] = __expf(row[k] - m); sum += e[k]; }
        float r = 1.f / sum;
#pragma unroll
        for (int k = 0; k < 16; ++k) CN[tid * 16 + k] = e[k] * r;
    }
    __syncthreads();

    half8 cf3 = { 0, 0, 0, 0, 0, 0, 0, 0 };
    if (kc < 2) {
#pragma unroll
        for (int j = 0; j < 8; ++j)
            cf3[j] = (_Float16)CN[n * 16 + kc * 8 + j];
    }

    f32x4 zf = { 0.f, 0.f, 0.f, 0.f };
    f32x4 aO[4];
#pragma unroll
    for (int i = 0; i < 4; ++i) aO[i] = zf;
    float nsqD[4] = { 0.f, 0.f, 0.f, 0.f };

    for (int it = 0; it < 32; ++it) {
        int f0 = it * 32;
#pragma unroll
        for (int p = 0; p < 8; ++p) {
            int r = p * 32 + (tid >> 3);
            int hj = tid & 7;
            int ll = r >> 4, b = r & 15;
            half4 v = *(const half4*)(
                Hp + ((size_t)(lg * 16 + ll) * 16 + b) * 1024 + f0 + hj * 4);
            *(half4*)(&Ht[r * 40 + hj * 4]) = v;
        }
#pragma unroll
        for (int p = 0; p < 8; ++p) {
            int idx = p * 256 + tid;
            int q = idx & 3, ff = (idx >> 2) & 31, k = idx >> 7;
            f32x4 v = *(const f32x4*)(
                wd + ((size_t)k * 1024 + f0 + ff) * 512 + d0 + q * 4);
#pragma unroll
            for (int j = 0; j < 4; ++j)
                Bh[(ff * 16 + q * 4 + j) * 24 + k] = (_Float16)v[j];
        }
        __syncthreads();
#pragma unroll
        for (int dl = 0; dl < 4; ++dl) {
            int d_l = w * 4 + dl;
#pragma unroll
            for (int fg = 0; fg < 2; ++fg) {
                half8 a = { 0, 0, 0, 0, 0, 0, 0, 0 };
                if (kc < 2)
                    a = *(const half8*)(&Bh[((fg * 16 + n) * 16 + d_l) * 24 + kc * 8]);
                f32x4 cw = MFMA_F16(a, cf3, zf, 0, 0, 0);
                nsqD[dl] += cw[0] * cw[0] + cw[1] * cw[1]
                          + cw[2] * cw[2] + cw[3] * cw[3];
                half4 h4 = { (_Float16)cw[0], (_Float16)cw[1],
                             (_Float16)cw[2], (_Float16)cw[3] };
                *(half4*)(&Wt[n * 528 + d_l * 32 + fg * 16 + kc * 4]) = h4;
            }
        }
        __syncthreads();
#pragma unroll
        for (int li = 0; li < 4; ++li) {
            int l = w * 4 + li;
            half8 hf = *(const half8*)(&Ht[(l * 16 + n) * 40 + kc * 8]);
            half8 wf = *(const half8*)(&Wt[l * 528 + n * 32 + kc * 8]);
            aO[li] = MFMA_F16(hf, wf, aO[li], 0, 0, 0);
        }
        __syncthreads();
    }

#pragma unroll
    for (int dl = 0; dl < 4; ++dl) {
        float v = nsqD[dl];
        v += __shfl_xor(v, 16); v += __shfl_xor(v, 32);
        if (kc == 0) CN[n * 16 + w * 4 + dl] = v;
    }
    __syncthreads();

#pragma unroll
    for (int li = 0; li < 4; ++li) {
        int lgl = lg * 16 + w * 4 + li;
        float r3 = 1.f / fmaxf(sqrtf(CN[(w * 4 + li) * 16 + n]), 1e-12f);
#pragma unroll
        for (int i = 0; i < 4; ++i)
            out[((size_t)(kc * 4 + i) * 128 + lgl) * 512 + d0 + n] = aO[li][i] * r3;
    }
}

__global__ __launch_bounds__(128) void final_kernel(float* __restrict__ out)
{
    int rid = blockIdx.x;
    int t = threadIdx.x;
    f32x4 y = *(const f32x4*)(out + (size_t)rid * 512 + t * 4);
    float s = y[0] * y[0] + y[1] * y[1] + y[2] * y[2] + y[3] * y[3];
#pragma unroll
    for (int off = 32; off > 0; off >>= 1) s += __shfl_down(s, off);
    __shared__ float sred[2];
    if ((t & 63) == 0) sred[t >> 6] = s;
    __syncthreads();
    float rr = 1.f / fmaxf(sqrtf(sred[0] + sred[1]), 1e-12f);
    f32x4 o = { y[0] * rr, y[1] * rr, y[2] * rr, y[3] * rr };
    *(f32x4*)(out + (size_t)rid * 512 + t * 4) = o;
}

// ---------------------------------------------------------------------------
extern "C" void kernel_launch(void* const* d_in, const int* in_sizes, int n_in,
                              void* d_out, int out_size, void* d_ws, size_t ws_size,
                              hipStream_t stream)
{
    (void)in_sizes; (void)n_in; (void)out_size;
    const float* x   = (const float*)d_in[0];
    const float* wg  = (const float*)d_in[1];
    const float* wu  = (const float*)d_in[2];
    const float* wd  = (const float*)d_in[3];
    const float* tc1 = (const float*)d_in[4];
    const float* tc2 = (const float*)d_in[5];
    const float* tc3 = (const float*)d_in[6];
    const float* usp = (const float*)d_in[7];
    const float* vsp = (const float*)d_in[8];
    float* outp = (float*)d_out;
    char* ws = (char*)d_ws;

    if (ws_size >= WS_FAST) {
        _Float16* P1  = (_Float16*)(ws + OFF_P1);
        _Float16* P2  = (_Float16*)(ws + OFF_P2);
        _Float16* P3n = (_Float16*)(ws + OFF_P3n);  // 17..33 MiB (after Np)
        _Float16* XA  = (_Float16*)(ws + OFF_XA);   // 32..34 MiB
        _Float16* U2  = (_Float16*)(ws + OFF_U2);   // 34..38 MiB
        _Float16* S   = (_Float16*)(ws + OFF_S);    // 38..42 MiB
        float* Rp = (float*)(ws + OFF_P1);   // overlays P1 (dead after up)
        float* Np = (float*)(ws + OFF_P2);   // 16..17 MiB (P2 dead after up)
        prep_basis_all<<<dim3(512, 2), dim3(256), 0, stream>>>(
            wg, wu, wd, P1, P2, P3n, 0);                   // P1, P2
        prep_x<<<dim3(256), dim3(256), 0, stream>>>(x, XA);
        up_split<<<dim3(512), dim3(512), 0, stream>>>(P1, P2, XA, tc1, tc2,
                                                      usp, vsp, U2, S);
        prep_basis_all<<<dim3(512, 1), dim3(256), 0, stream>>>(
            wg, wu, wd, P1, P2, P3n, 2);                   // P3 at 17 MiB
        down_fast<<<dim3(512), dim3(512), 0, stream>>>(P3n, tc3, S, U2, Rp, Np);
        final_combine<<<dim3(2048), dim3(128), 0, stream>>>(Rp, Np, outp);
    } else {
        _Float16* Hp = (_Float16*)ws;
        up_kernel<<<dim3(512), dim3(256), 0, stream>>>(x, wg, wu, tc1, tc2,
                                                       usp, vsp, Hp);
        down_kernel<<<dim3(256), dim3(256), 0, stream>>>(wd, tc3, Hp, outp);
        final_kernel<<<dim3(2048), dim3(128), 0, stream>>>(outp);
    }
}

// Round 10
// 229.251 us; speedup vs baseline: 1.0774x; 1.0458x over previous
//
#include <hip/hip_runtime.h>
#include <hip/hip_bf16.h>
#include <cmath>

// ---------------------------------------------------------------------------
// NPerTokenSwishGLU_Basis — fused f16-MFMA implementation (gfx950), round 17.
//
// R16 post-mortem: 512-thr tile-doubling regressed (58.5us up, 239.7 total):
// (a) Wt l-stride 1168 halves = 584 dw == 8 mod 32 -> 4-bank mix writes,
// conflicts 2.25M->6.57M; (b) even net of that, byte-halving didn't pay —
// the 512-thr shape loses more than the traffic saving returns. R15 (dist-2
// prefetch) also regressed via (256,4)'s hard 64-VGPR grant + spill.
// R17: strict revert to the proven best (R14, 225.0us): 256-thr (256,4)
// kernels, K=16 mix MFMA, rolled loops, LDS_BARRIER, stride-584 Wt (292 dw
// == 4 mod 32, conflict-free). This re-anchors the baseline.
// ---------------------------------------------------------------------------

typedef _Float16 half8 __attribute__((ext_vector_type(8)));
typedef _Float16 half4 __attribute__((ext_vector_type(4)));
typedef float    f32x4 __attribute__((ext_vector_type(4)));
typedef float    f32x2 __attribute__((ext_vector_type(2)));

#define MFMA_F16  __builtin_amdgcn_mfma_f32_16x16x32_f16
#define MFMA16    __builtin_amdgcn_mfma_f32_16x16x16f16

// LDS-only barrier: drain DS ops, leave global loads in flight.
#define LDS_BARRIER()                                           \
    do {                                                        \
        asm volatile("s_waitcnt lgkmcnt(0)" ::: "memory");      \
        __builtin_amdgcn_s_barrier();                           \
    } while (0)

static constexpr size_t OFF_P1  = 0;            // 16 MiB; Rp overlay (down)
static constexpr size_t OFF_P2  = 16777216;     // 16 MiB; Np overlay (down, 1 MiB)
static constexpr size_t OFF_P3n = 17825792;     // 16 MiB at 17 MiB (after Np)
static constexpr size_t OFF_XA  = 33554432;     // 2 MiB at 32 MiB
static constexpr size_t OFF_U2  = 35651584;     // 4 MiB at 34 MiB
static constexpr size_t OFF_S   = 39845888;     // 4 MiB at 38 MiB (top 42 MiB)
static constexpr size_t WS_FAST = 54525952;     // 52 MiB (proven)

// ---------------------------------------------------------------------------
// prep (two-sided coalesced transpose), 32x32 tiles (R13):
//   z=0,1: wg/wu (K,512,1024)=[k][d][f] -> P[f][d][k]
//   z=2  : wd    (K,1024,512)=[k][f][d] -> P3[d][f][k]
// ---------------------------------------------------------------------------
__global__ __launch_bounds__(256) void prep_basis_all(
    const float* __restrict__ wg, const float* __restrict__ wu,
    const float* __restrict__ wd,
    _Float16* __restrict__ P1, _Float16* __restrict__ P2,
    _Float16* __restrict__ P3, int zoff)
{
    int z = blockIdx.y + zoff;
    const float* src = (z == 0) ? wg : (z == 1) ? wu : wd;
    _Float16*    dst = (z == 0) ? P1 : (z == 1) ? P2 : P3;
    int Amin = (z == 2) ? 1024 : 512;    // minor-dim size
    int Bmaj = (z == 2) ? 512 : 1024;    // major-dim size
    int nM = Bmaj >> 5;
    int m0 = (blockIdx.x / nM) * 32;     // minor base
    int M0 = (blockIdx.x % nM) * 32;     // major base

    __shared__ float S[16 * 1088];       // [k][row*34 + col]
    int t = threadIdx.x;

    int row = t >> 3;                    // 0..31 (minor row)
    int cg  = t & 7;                     // 0..7 (16B col group)
#pragma unroll
    for (int k = 0; k < 16; ++k) {
        f32x4 v = *(const f32x4*)(
            src + (size_t)k * Amin * Bmaj + (size_t)(m0 + row) * Bmaj + M0 + cg * 4);
        f32x2 lo = { v[0], v[1] };
        f32x2 hi = { v[2], v[3] };
        *(f32x2*)(&S[k * 1088 + row * 34 + cg * 4])     = lo;
        *(f32x2*)(&S[k * 1088 + row * 34 + cg * 4 + 2]) = hi;
    }
    __syncthreads();

    int mn = t & 31, mjq = t >> 5;
#pragma unroll
    for (int q = 0; q < 4; ++q) {
        int mj = q * 8 + mjq;
        half8 v0, v1;
#pragma unroll
        for (int k = 0; k < 8; ++k) v0[k] = (_Float16)S[k * 1088 + mn * 34 + mj];
#pragma unroll
        for (int k = 0; k < 8; ++k) v1[k] = (_Float16)S[(k + 8) * 1088 + mn * 34 + mj];
        _Float16* out = dst + ((size_t)(M0 + mj) * Amin + m0 + mn) * 16;
        *(half8*)out       = v0;
        *(half8*)(out + 8) = v1;
    }
}

// ---------------------------------------------------------------------------
// prep_x: x fp32 [b][l][d] -> XA f16 [l][d>>3][b][8]
// grid 256 = 128 l x 2 b-halves, 256 threads.
// ---------------------------------------------------------------------------
__global__ __launch_bounds__(256) void prep_x(
    const float* __restrict__ x, _Float16* __restrict__ XA)
{
    int l = blockIdx.x >> 1, bh = blockIdx.x & 1;
    __shared__ __align__(16) _Float16 XT[8][524];
    int t = threadIdx.x;

    int bl = t >> 5, q = t & 31;          // b-local 0..7, q 0..31
    int b = bh * 8 + bl;
#pragma unroll
    for (int j = 0; j < 4; ++j) {
        f32x4 v = *(const f32x4*)(x + ((size_t)(b * 128 + l) * 512 + j * 128 + q * 4));
#pragma unroll
        for (int i = 0; i < 4; ++i)
            XT[bl][j * 128 + q * 4 + i] = (_Float16)v[i];
    }
    __syncthreads();

    int c = t >> 2, bi = t & 3;           // c 0..63
#pragma unroll
    for (int s = 0; s < 2; ++s) {
        int blw = bi * 2 + s;             // 0..7
        half8 h = *(const half8*)(&XT[blw][c * 8]);
        *(half8*)(XA + (((size_t)(l * 64 + c) * 16 + bh * 8 + blw) * 8)) = h;
    }
}

// ---------------------------------------------------------------------------
// up_split (R17 = R14): 1024 blocks = mh(2) x 8 lg x 64 f-tiles, 256 thr.
// Mix uses 16x16x16 MFMA; in-loop barrier is LDS_BARRIER (global loads stay
// in flight). LDS: Wt[2][16*584] + CN -> 4 blocks/CU.
// ---------------------------------------------------------------------------
__global__ __launch_bounds__(256, 4) void up_split(
    const _Float16* __restrict__ P1, const _Float16* __restrict__ P2,
    const _Float16* __restrict__ XA,
    const float* __restrict__ tc1, const float* __restrict__ tc2,
    const float* __restrict__ usp, const float* __restrict__ vsp,
    _Float16* __restrict__ U2, _Float16* __restrict__ S)
{
    int bid = blockIdx.x;
    int mh = bid >> 9;                  // 0: gate/u, 1: up/v
    int lg = (bid >> 6) & 7;
    int f0 = (bid & 63) * 16;
    int tid = threadIdx.x;
    int w = tid >> 6, lane = tid & 63;
    int n = lane & 15, kc = lane >> 4;

    const _Float16* P  = mh ? P2 : P1;
    const float*    tc = mh ? tc2 : tc1;

    __shared__ __align__(16) _Float16 Wt[2][16 * 584]; // [buf][l*584+f*36+d]
    __shared__ float CN[256];

    // element-unit base pointers (advance +512 per 32-d chunk)
    const _Float16* pP  = P + ((size_t)(f0 + w * 4) * 512 + n) * 16 + kc * 4;
    const _Float16* pXA = XA + (((size_t)(lg * 16 + w * 4) * 64 + kc) * 16 + n) * 8;

    half4 pa[4][2];
    // ---- prologue: issue pa(0); softmax + barrier cover the latency ----
#pragma unroll
    for (int fl = 0; fl < 4; ++fl)
#pragma unroll
        for (int dg = 0; dg < 2; ++dg)
            pa[fl][dg] = *(const half4*)(pP + fl * 8192 + dg * 256);
    const _Float16* qP = pP + 512;

    if (tid < 16) {
        const float* row = tc + (size_t)(lg * 16 + tid) * 16;
        float e[16], m = -1e30f, sum = 0.f;
#pragma unroll
        for (int k = 0; k < 16; ++k) m = fmaxf(m, row[k]);
#pragma unroll
        for (int k = 0; k < 16; ++k) { e[k] = __expf(row[k] - m); sum += e[k]; }
        float r = 1.f / sum;
#pragma unroll
        for (int k = 0; k < 16; ++k) CN[tid * 16 + k] = e[k] * r;
    }
    __syncthreads();

    half4 cf;
#pragma unroll
    for (int j = 0; j < 4; ++j)
        cf[j] = (_Float16)CN[n * 16 + kc * 4 + j];

    f32x4 zf = { 0.f, 0.f, 0.f, 0.f };
    f32x4 aU[4];
#pragma unroll
    for (int i = 0; i < 4; ++i) aU[i] = zf;
    float nsq[4] = { 0.f, 0.f, 0.f, 0.f };
    half8 xf[4];

#pragma unroll 1
    for (int it = 0; it < 16; ++it) {
        _Float16* WtW = &Wt[it & 1][0];
        const _Float16* WtR = &Wt[(it & 1) ^ 1][0];

        // ---- mix(it) (pa in flight; compiler waits vmcnt), K=16 MFMA ----
#pragma unroll
        for (int fl = 0; fl < 4; ++fl) {
            int f_l = w * 4 + fl;
#pragma unroll
            for (int dg = 0; dg < 2; ++dg) {
                f32x4 c1 = MFMA16(pa[fl][dg], cf, zf, 0, 0, 0);
                nsq[fl] += c1[0] * c1[0] + c1[1] * c1[1]
                         + c1[2] * c1[2] + c1[3] * c1[3];
                half4 h1 = { (_Float16)c1[0], (_Float16)c1[1],
                             (_Float16)c1[2], (_Float16)c1[3] };
                *(half4*)(&WtW[n * 584 + f_l * 36 + dg * 16 + kc * 4]) = h1;
            }
        }
        // ---- issue pa(it+1) into freed regs ----
        if (it < 15) {
#pragma unroll
            for (int fl = 0; fl < 4; ++fl)
#pragma unroll
                for (int dg = 0; dg < 2; ++dg)
                    pa[fl][dg] = *(const half4*)(qP + fl * 8192 + dg * 256);
        }
        // ---- consume(it-1) from the other buffer ----
        if (it > 0) {
#pragma unroll
            for (int li = 0; li < 4; ++li) {
                int l = w * 4 + li;
                half8 wU = *(const half8*)(&WtR[l * 584 + n * 36 + kc * 8]);
                aU[li] = MFMA_F16(xf[li], wU, aU[li], 0, 0, 0);
            }
        }
        // ---- load xf(it): 1KB dense per wave ----
#pragma unroll
        for (int li = 0; li < 4; ++li)
            xf[li] = *(const half8*)(pXA + li * 8192);
        pXA += 512;
        qP += 512;
        LDS_BARRIER();   // drain DS only; global prefetches stay in flight
    }
    // ---- tail consume (chunk 15, buffer 1) ----
#pragma unroll
    for (int li = 0; li < 4; ++li) {
        int l = w * 4 + li;
        half8 wU = *(const half8*)(&Wt[1][l * 584 + n * 36 + kc * 8]);
        aU[li] = MFMA_F16(xf[li], wU, aU[li], 0, 0, 0);
    }

    // ---- norm reduce ----
#pragma unroll
    for (int fl = 0; fl < 4; ++fl) {
        float vU = nsq[fl];
        vU += __shfl_xor(vU, 16); vU += __shfl_xor(vU, 32);
        if (kc == 0) CN[n * 16 + w * 4 + fl] = vU;
    }
    __syncthreads();

    int f = f0 + n;
    float sc = mh ? (fabsf(vsp[f]) * 22.627416997969522f)   // vs = |vsp|*sqrt(512)
                  : fabsf(usp[f]);                          // us = |usp|
    _Float16* Out = mh ? S : U2;
#pragma unroll
    for (int li = 0; li < 4; ++li) {
        int lgl = lg * 16 + w * 4 + li;
        float r1 = 1.f / fmaxf(sqrtf(CN[(w * 4 + li) * 16 + n]), 1e-12f);
#pragma unroll
        for (int i = 0; i < 4; ++i) {
            float val = aU[li][i] * r1 * sc;       // us*u'  or  vs*v'
            if (mh) val = val / (1.f + __expf(-val));   // silu(vs*v')
            // layout [l][f>>3][b][8]
            Out[(((size_t)lgl * 128 + (f >> 3)) * 16 + kc * 4 + i) * 8 + (f & 7)] =
                (_Float16)val;
        }
    }
}

// ---------------------------------------------------------------------------
// down_fast (R17 = R14): 1024 blocks = 4 f-quarters x 8 lg x 32 d-tiles.
// LDS_BARRIER in-loop; __launch_bounds__(256,4).
// ---------------------------------------------------------------------------
__global__ __launch_bounds__(256, 4) void down_fast(
    const _Float16* __restrict__ P3, const float* __restrict__ tc3,
    const _Float16* __restrict__ S, const _Float16* __restrict__ U2,
    float* __restrict__ Rp, float* __restrict__ Np)
{
    int zh = blockIdx.x >> 8;          // 0..3
    int rem = blockIdx.x & 255;
    int lg = rem >> 5;
    int d0 = (rem & 31) * 16;
    int tid = threadIdx.x;
    int w = tid >> 6, lane = tid & 63;
    int n = lane & 15, kc = lane >> 4;

    __shared__ __align__(16) _Float16 Wt[2][16 * 584];    // [buf][l*584 + d*36 + f]
    __shared__ float CN[256];

    // element-unit base pointers (advance +512 per 32-f chunk)
    const _Float16* pP3 = P3 + ((size_t)(d0 + w * 4) * 1024 + zh * 256 + n) * 16 + kc * 4;
    size_t hoff = (((size_t)(lg * 16 + w * 4) * 128 + zh * 32 + kc) * 16 + n) * 8;
    const _Float16* pS = S + hoff;
    const _Float16* pU = U2 + hoff;

    half4 pa[4][2];
    // ---- prologue: issue pa(0) ----
#pragma unroll
    for (int dl = 0; dl < 4; ++dl)
#pragma unroll
        for (int fg = 0; fg < 2; ++fg)
            pa[dl][fg] = *(const half4*)(pP3 + dl * 16384 + fg * 256);
    const _Float16* qP3 = pP3 + 512;

    if (tid < 16) {
        const float* row = tc3 + (size_t)(lg * 16 + tid) * 16;
        float e[16], m = -1e30f, sum = 0.f;
#pragma unroll
        for (int k = 0; k < 16; ++k) m = fmaxf(m, row[k]);
#pragma unroll
        for (int k = 0; k < 16; ++k) { e[k] = __expf(row[k] - m); sum += e[k]; }
        float r = 1.f / sum;
#pragma unroll
        for (int k = 0; k < 16; ++k) CN[tid * 16 + k] = e[k] * r;
    }
    __syncthreads();

    half4 cf3;
#pragma unroll
    for (int j = 0; j < 4; ++j)
        cf3[j] = (_Float16)CN[n * 16 + kc * 4 + j];

    f32x4 zf = { 0.f, 0.f, 0.f, 0.f };
    f32x4 aO[4];
#pragma unroll
    for (int i = 0; i < 4; ++i) aO[i] = zf;
    float nsqD[4] = { 0.f, 0.f, 0.f, 0.f };
    half8 hf[4];

#pragma unroll 1
    for (int it = 0; it < 8; ++it) {
        _Float16* WtW = &Wt[it & 1][0];
        const _Float16* WtR = &Wt[(it & 1) ^ 1][0];

        // ---- mix(it), K=16 MFMA ----
#pragma unroll
        for (int dl = 0; dl < 4; ++dl) {
            int d_l = w * 4 + dl;
#pragma unroll
            for (int fg = 0; fg < 2; ++fg) {
                f32x4 cw = MFMA16(pa[dl][fg], cf3, zf, 0, 0, 0);
                nsqD[dl] += cw[0] * cw[0] + cw[1] * cw[1]
                          + cw[2] * cw[2] + cw[3] * cw[3];
                half4 h4 = { (_Float16)cw[0], (_Float16)cw[1],
                             (_Float16)cw[2], (_Float16)cw[3] };
                *(half4*)(&WtW[n * 584 + d_l * 36 + fg * 16 + kc * 4]) = h4;
            }
        }
        // ---- issue pa(it+1) ----
        if (it < 7) {
#pragma unroll
            for (int dl = 0; dl < 4; ++dl)
#pragma unroll
                for (int fg = 0; fg < 2; ++fg)
                    pa[dl][fg] = *(const half4*)(qP3 + dl * 16384 + fg * 256);
        }
        // ---- consume(it-1) ----
        if (it > 0) {
#pragma unroll
            for (int li = 0; li < 4; ++li) {
                int l = w * 4 + li;
                half8 wf = *(const half8*)(&WtR[l * 584 + n * 36 + kc * 8]);
                aO[li] = MFMA_F16(hf[li], wf, aO[li], 0, 0, 0);
            }
        }
        // ---- load hf(it) = S * U2 (each 1KB dense per wave) ----
#pragma unroll
        for (int li = 0; li < 4; ++li) {
            half8 s8 = *(const half8*)(pS + li * 16384);
            half8 u8 = *(const half8*)(pU + li * 16384);
            hf[li] = s8 * u8;
        }
        pS += 512;
        pU += 512;
        qP3 += 512;
        LDS_BARRIER();   // drain DS only; global prefetches stay in flight
    }
    // ---- tail consume (chunk 7, buffer 1) ----
#pragma unroll
    for (int li = 0; li < 4; ++li) {
        int l = w * 4 + li;
        half8 wf = *(const half8*)(&Wt[1][l * 584 + n * 36 + kc * 8]);
        aO[li] = MFMA_F16(hf[li], wf, aO[li], 0, 0, 0);
    }

#pragma unroll
    for (int dl = 0; dl < 4; ++dl) {
        float v = nsqD[dl];
        v += __shfl_xor(v, 16); v += __shfl_xor(v, 32);
        if (kc == 0)
            Np[(size_t)zh * 65536 + (size_t)(lg * 16 + n) * 512 + d0 + w * 4 + dl] = v;
    }
#pragma unroll
    for (int li = 0; li < 4; ++li) {
        int lgl = lg * 16 + w * 4 + li;
#pragma unroll
        for (int i = 0; i < 4; ++i)
            Rp[(size_t)zh * 1048576 +
               ((size_t)(kc * 4 + i) * 128 + lgl) * 512 + d0 + n] = aO[li][i];
    }
}

// ---------------------------------------------------------------------------
__global__ __launch_bounds__(128) void final_combine(
    const float* __restrict__ Rp, const float* __restrict__ Np,
    float* __restrict__ out)
{
    int rid = blockIdx.x;              // b*128 + l
    int l = rid & 127;
    int t = threadIdx.x;
    f32x4 r = { 0.f, 0.f, 0.f, 0.f };
    f32x4 nn = { 0.f, 0.f, 0.f, 0.f };
#pragma unroll
    for (int zh = 0; zh < 4; ++zh) {
        f32x4 rz = *(const f32x4*)(Rp + (size_t)zh * 1048576 + (size_t)rid * 512 + t * 4);
        f32x4 nz = *(const f32x4*)(Np + (size_t)zh * 65536 + (size_t)l * 512 + t * 4);
#pragma unroll
        for (int j = 0; j < 4; ++j) { r[j] += rz[j]; nn[j] += nz[j]; }
    }
    f32x4 y;
#pragma unroll
    for (int j = 0; j < 4; ++j) {
        float rr = 1.f / fmaxf(sqrtf(fmaxf(nn[j], 0.f)), 1e-12f);
        y[j] = r[j] * rr;
    }
    float s = y[0] * y[0] + y[1] * y[1] + y[2] * y[2] + y[3] * y[3];
#pragma unroll
    for (int off = 32; off > 0; off >>= 1) s += __shfl_down(s, off);
    __shared__ float sred[2];
    if ((t & 63) == 0) sred[t >> 6] = s;
    __syncthreads();
    float rr = 1.f / fmaxf(sqrtf(sred[0] + sred[1]), 1e-12f);
    f32x4 o = { y[0] * rr, y[1] * rr, y[2] * rr, y[3] * rr };
    *(f32x4*)(out + (size_t)rid * 512 + t * 4) = o;
}

// ===========================================================================
// SLOW FALLBACK (round-2 kernels, proven) — used when ws_size < WS_FAST
// ===========================================================================
__global__ __launch_bounds__(256) void up_kernel(
    const float* __restrict__ x,
    const float* __restrict__ wg, const float* __restrict__ wu,
    const float* __restrict__ tc1, const float* __restrict__ tc2,
    const float* __restrict__ usp, const float* __restrict__ vsp,
    _Float16* __restrict__ Hp)
{
    int lg = blockIdx.x >> 6;
    int f0 = (blockIdx.x & 63) * 16;
    int tid = threadIdx.x;
    int w = tid >> 6, lane = tid & 63;
    int n = lane & 15, kc = lane >> 4;

    __shared__ __align__(16) _Float16 Xt[256 * 40];
    __shared__ __align__(16) _Float16 Bh[32 * 16 * 24];
    __shared__ __align__(16) _Float16 Wt[16 * 528];
    __shared__ float CN[2 * 16 * 16];

    if (tid < 32) {
        int s = tid >> 4, ll = tid & 15;
        const float* row = (s ? tc2 : tc1) + (size_t)(lg * 16 + ll) * 16;
        float e[16], m = -1e30f, sum = 0.f;
#pragma unroll
        for (int k = 0; k < 16; ++k) m = fmaxf(m, row[k]);
#pragma unroll
        for (int k = 0; k < 16; ++k) { e[k] = __expf(row[k] - m); sum += e[k]; }
        float r = 1.f / sum;
#pragma unroll
        for (int k = 0; k < 16; ++k) CN[s * 256 + ll * 16 + k] = e[k] * r;
    }
    __syncthreads();

    half8 cf1 = { 0, 0, 0, 0, 0, 0, 0, 0 };
    half8 cf2 = { 0, 0, 0, 0, 0, 0, 0, 0 };
    if (kc < 2) {
#pragma unroll
        for (int j = 0; j < 8; ++j) {
            cf1[j] = (_Float16)CN[0 * 256 + n * 16 + kc * 8 + j];
            cf2[j] = (_Float16)CN[1 * 256 + n * 16 + kc * 8 + j];
        }
    }

    f32x4 zf = { 0.f, 0.f, 0.f, 0.f };
    f32x4 aU[4], aV[4];
#pragma unroll
    for (int i = 0; i < 4; ++i) { aU[i] = zf; aV[i] = zf; }
    float nsqU[4] = { 0.f, 0.f, 0.f, 0.f };
    float nsqV[4] = { 0.f, 0.f, 0.f, 0.f };

    for (int it = 0; it < 16; ++it) {
        int d0 = it * 32;
#pragma unroll
        for (int p = 0; p < 8; ++p) {
            int r = p * 32 + (tid >> 3);
            int fj = tid & 7;
            int ll = r >> 4, b = r & 15;
            f32x4 v = *(const f32x4*)(
                x + ((size_t)(b * 128 + lg * 16 + ll) * 512 + d0 + fj * 4));
            half4 h = { (_Float16)v[0], (_Float16)v[1],
                        (_Float16)v[2], (_Float16)v[3] };
            *(half4*)(&Xt[r * 40 + fj * 4]) = h;
        }
#pragma unroll
        for (int p = 0; p < 8; ++p) {
            int idx = p * 256 + tid;
            int q = idx & 3, dd = (idx >> 2) & 31, k = idx >> 7;
            f32x4 v = *(const f32x4*)(
                wg + ((size_t)k * 512 + d0 + dd) * 1024 + f0 + q * 4);
#pragma unroll
            for (int j = 0; j < 4; ++j)
                Bh[(dd * 16 + q * 4 + j) * 24 + k] = (_Float16)v[j];
        }
        __syncthreads();
#pragma unroll
        for (int fl = 0; fl < 4; ++fl) {
            int f_l = w * 4 + fl;
#pragma unroll
            for (int dg = 0; dg < 2; ++dg) {
                half8 a = { 0, 0, 0, 0, 0, 0, 0, 0 };
                if (kc < 2)
                    a = *(const half8*)(&Bh[((dg * 16 + n) * 16 + f_l) * 24 + kc * 8]);
                f32x4 cw = MFMA_F16(a, cf1, zf, 0, 0, 0);
                nsqU[fl] += cw[0] * cw[0] + cw[1] * cw[1]
                          + cw[2] * cw[2] + cw[3] * cw[3];
                half4 h4 = { (_Float16)cw[0], (_Float16)cw[1],
                             (_Float16)cw[2], (_Float16)cw[3] };
                *(half4*)(&Wt[n * 528 + f_l * 32 + dg * 16 + kc * 4]) = h4;
            }
        }
        __syncthreads();
#pragma unroll
        for (int li = 0; li < 4; ++li) {
            int l = w * 4 + li;
            half8 xf = *(const half8*)(&Xt[(l * 16 + n) * 40 + kc * 8]);
            half8 wf = *(const half8*)(&Wt[l * 528 + n * 32 + kc * 8]);
            aU[li] = MFMA_F16(xf, wf, aU[li], 0, 0, 0);
        }
#pragma unroll
        for (int p = 0; p < 8; ++p) {
            int idx = p * 256 + tid;
            int q = idx & 3, dd = (idx >> 2) & 31, k = idx >> 7;
            f32x4 v = *(const f32x4*)(
                wu + ((size_t)k * 512 + d0 + dd) * 1024 + f0 + q * 4);
#pragma unroll
            for (int j = 0; j < 4; ++j)
                Bh[(dd * 16 + q * 4 + j) * 24 + k] = (_Float16)v[j];
        }
        __syncthreads();
#pragma unroll
        for (int fl = 0; fl < 4; ++fl) {
            int f_l = w * 4 + fl;
#pragma unroll
            for (int dg = 0; dg < 2; ++dg) {
                half8 a = { 0, 0, 0, 0, 0, 0, 0, 0 };
                if (kc < 2)
                    a = *(const half8*)(&Bh[((dg * 16 + n) * 16 + f_l) * 24 + kc * 8]);
                f32x4 cw = MFMA_F16(a, cf2, zf, 0, 0, 0);
                nsqV[fl] += cw[0] * cw[0] + cw[1] * cw[1]
                          + cw[2] * cw[2] + cw[3] * cw[3];
                half4 h4 = { (_Float16)cw[0], (_Float16)cw[1],
                             (_Float16)cw[2], (_Float16)cw[3] };
                *(half4*)(&Wt[n * 528 + f_l * 32 + dg * 16 + kc * 4]) = h4;
            }
        }
        __syncthreads();
#pragma unroll
        for (int li = 0; li < 4; ++li) {
            int l = w * 4 + li;
            half8 xf = *(const half8*)(&Xt[(l * 16 + n) * 40 + kc * 8]);
            half8 wf = *(const half8*)(&Wt[l * 528 + n * 32 + kc * 8]);
            aV[li] = MFMA_F16(xf, wf, aV[li], 0, 0, 0);
        }
        __syncthreads();
    }

#pragma unroll
    for (int fl = 0; fl < 4; ++fl) {
        float vU = nsqU[fl], vV = nsqV[fl];
        vU += __shfl_xor(vU, 16); vU += __shfl_xor(vU, 32);
        vV += __shfl_xor(vV, 16); vV += __shfl_xor(vV, 32);
        if (kc == 0) {
            CN[0 * 256 + n * 16 + w * 4 + fl] = vU;
            CN[1 * 256 + n * 16 + w * 4 + fl] = vV;
        }
    }
    __syncthreads();

    int f = f0 + n;
    float usv = fabsf(usp[f]);
    float vsv = fabsf(vsp[f]) * 22.627416997969522f;
#pragma unroll
    for (int li = 0; li < 4; ++li) {
        int lgl = lg * 16 + w * 4 + li;
        float r1 = 1.f / fmaxf(sqrtf(CN[0 * 256 + (w * 4 + li) * 16 + n]), 1e-12f);
        float r2 = 1.f / fmaxf(sqrtf(CN[1 * 256 + (w * 4 + li) * 16 + n]), 1e-12f);
#pragma unroll
        for (int i = 0; i < 4; ++i) {
            float u = aU[li][i] * r1;
            float v = aV[li][i] * r2;
            float zz = vsv * v;
            float sil = zz / (1.f + __expf(-zz));
            float h = sil * (usv * u);
            Hp[((size_t)lgl * 16 + kc * 4 + i) * 1024 + f] = (_Float16)h;
        }
    }
}

__global__ __launch_bounds__(256) void down_kernel(
    const float* __restrict__ wd, const float* __restrict__ tc3,
    const _Float16* __restrict__ Hp, float* __restrict__ out)
{
    int lg = blockIdx.x >> 5;
    int d0 = (blockIdx.x & 31) * 16;
    int tid = threadIdx.x;
    int w = tid >> 6, lane = tid & 63;
    int n = lane & 15, kc = lane >> 4;

    __shared__ __align__(16) _Float16 Ht[256 * 40];
    __shared__ __align__(16) _Float16 Bh[32 * 16 * 24];
    __shared__ __align__(16) _Float16 Wt[16 * 528];
    __shared__ float CN[16 * 16];

    if (tid < 16) {
        const float* row = tc3 + (size_t)(lg * 16 + tid) * 16;
        float e[16], m = -1e30f, sum = 0.f;
#pragma unroll
        for (int k = 0; k < 16; ++k) m = fmaxf(m, row[k]);
#pragma unroll
        for (int k = 0; k < 16; ++k) { e[k] = __expf(row[k] - m); sum += e[k]; }
        float r = 1.f / sum;
#pragma unroll
        for (int k = 0; k < 16; ++k) CN[tid * 16 + k] = e[k] * r;
    }
    __syncthreads();

    half8 cf3 = { 0, 0, 0, 0, 0, 0, 0, 0 };
    if (kc < 2) {
#pragma unroll
        for (int j = 0; j < 8; ++j)
            cf3[j] = (_Float16)CN[n * 16 + kc * 8 + j];
    }

    f32x4 zf = { 0.f, 0.f, 0.f, 0.f };
    f32x4 aO[4];
#pragma unroll
    for (int i = 0; i < 4; ++i) aO[i] = zf;
    float nsqD[4] = { 0.f, 0.f, 0.f, 0.f };

    for (int it = 0; it < 32; ++it) {
        int f0 = it * 32;
#pragma unroll
        for (int p = 0; p < 8; ++p) {
            int r = p * 32 + (tid >> 3);
            int hj = tid & 7;
            int ll = r >> 4, b = r & 15;
            half4 v = *(const half4*)(
                Hp + ((size_t)(lg * 16 + ll) * 16 + b) * 1024 + f0 + hj * 4);
            *(half4*)(&Ht[r * 40 + hj * 4]) = v;
        }
#pragma unroll
        for (int p = 0; p < 8; ++p) {
            int idx = p * 256 + tid;
            int q = idx & 3, ff = (idx >> 2) & 31, k = idx >> 7;
            f32x4 v = *(const f32x4*)(
                wd + ((size_t)k * 1024 + f0 + ff) * 512 + d0 + q * 4);
#pragma unroll
            for (int j = 0; j < 4; ++j)
                Bh[(ff * 16 + q * 4 + j) * 24 + k] = (_Float16)v[j];
        }
        __syncthreads();
#pragma unroll
        for (int dl = 0; dl < 4; ++dl) {
            int d_l = w * 4 + dl;
#pragma unroll
            for (int fg = 0; fg < 2; ++fg) {
                half8 a = { 0, 0, 0, 0, 0, 0, 0, 0 };
                if (kc < 2)
                    a = *(const half8*)(&Bh[((fg * 16 + n) * 16 + d_l) * 24 + kc * 8]);
                f32x4 cw = MFMA_F16(a, cf3, zf, 0, 0, 0);
                nsqD[dl] += cw[0] * cw[0] + cw[1] * cw[1]
                          + cw[2] * cw[2] + cw[3] * cw[3];
                half4 h4 = { (_Float16)cw[0], (_Float16)cw[1],
                             (_Float16)cw[2], (_Float16)cw[3] };
                *(half4*)(&Wt[n * 528 + d_l * 32 + fg * 16 + kc * 4]) = h4;
            }
        }
        __syncthreads();
#pragma unroll
        for (int li = 0; li < 4; ++li) {
            int l = w * 4 + li;
            half8 hf = *(const half8*)(&Ht[(l * 16 + n) * 40 + kc * 8]);
            half8 wf = *(const half8*)(&Wt[l * 528 + n * 32 + kc * 8]);
            aO[li] = MFMA_F16(hf, wf, aO[li], 0, 0, 0);
        }
        __syncthreads();
    }

#pragma unroll
    for (int dl = 0; dl < 4; ++dl) {
        float v = nsqD[dl];
        v += __shfl_xor(v, 16); v += __shfl_xor(v, 32);
        if (kc == 0) CN[n * 16 + w * 4 + dl] = v;
    }
    __syncthreads();

#pragma unroll
    for (int li = 0; li < 4; ++li) {
        int lgl = lg * 16 + w * 4 + li;
        float r3 = 1.f / fmaxf(sqrtf(CN[(w * 4 + li) * 16 + n]), 1e-12f);
#pragma unroll
        for (int i = 0; i < 4; ++i)
            out[((size_t)(kc * 4 + i) * 128 + lgl) * 512 + d0 + n] = aO[li][i] * r3;
    }
}

__global__ __launch_bounds__(128) void final_kernel(float* __restrict__ out)
{
    int rid = blockIdx.x;
    int t = threadIdx.x;
    f32x4 y = *(const f32x4*)(out + (size_t)rid * 512 + t * 4);
    float s = y[0] * y[0] + y[1] * y[1] + y[2] * y[2] + y[3] * y[3];
#pragma unroll
    for (int off = 32; off > 0; off >>= 1) s += __shfl_down(s, off);
    __shared__ float sred[2];
    if ((t & 63) == 0) sred[t >> 6] = s;
    __syncthreads();
    float rr = 1.f / fmaxf(sqrtf(sred[0] + sred[1]), 1e-12f);
    f32x4 o = { y[0] * rr, y[1] * rr, y[2] * rr, y[3] * rr };
    *(f32x4*)(out + (size_t)rid * 512 + t * 4) = o;
}

// ---------------------------------------------------------------------------
extern "C" void kernel_launch(void* const* d_in, const int* in_sizes, int n_in,
                              void* d_out, int out_size, void* d_ws, size_t ws_size,
                              hipStream_t stream)
{
    (void)in_sizes; (void)n_in; (void)out_size;
    const float* x   = (const float*)d_in[0];
    const float* wg  = (const float*)d_in[1];
    const float* wu  = (const float*)d_in[2];
    const float* wd  = (const float*)d_in[3];
    const float* tc1 = (const float*)d_in[4];
    const float* tc2 = (const float*)d_in[5];
    const float* tc3 = (const float*)d_in[6];
    const float* usp = (const float*)d_in[7];
    const float* vsp = (const float*)d_in[8];
    float* outp = (float*)d_out;
    char* ws = (char*)d_ws;

    if (ws_size >= WS_FAST) {
        _Float16* P1  = (_Float16*)(ws + OFF_P1);
        _Float16* P2  = (_Float16*)(ws + OFF_P2);
        _Float16* P3n = (_Float16*)(ws + OFF_P3n);  // 17..33 MiB (after Np)
        _Float16* XA  = (_Float16*)(ws + OFF_XA);   // 32..34 MiB
        _Float16* U2  = (_Float16*)(ws + OFF_U2);   // 34..38 MiB
        _Float16* S   = (_Float16*)(ws + OFF_S);    // 38..42 MiB
        float* Rp = (float*)(ws + OFF_P1);   // overlays P1 (dead after up)
        float* Np = (float*)(ws + OFF_P2);   // 16..17 MiB (P2 dead after up)
        prep_basis_all<<<dim3(512, 2), dim3(256), 0, stream>>>(
            wg, wu, wd, P1, P2, P3n, 0);                   // P1, P2
        prep_x<<<dim3(256), dim3(256), 0, stream>>>(x, XA);
        up_split<<<dim3(1024), dim3(256), 0, stream>>>(P1, P2, XA, tc1, tc2,
                                                       usp, vsp, U2, S);
        prep_basis_all<<<dim3(512, 1), dim3(256), 0, stream>>>(
            wg, wu, wd, P1, P2, P3n, 2);                   // P3 at 17 MiB
        down_fast<<<dim3(1024), dim3(256), 0, stream>>>(P3n, tc3, S, U2, Rp, Np);
        final_combine<<<dim3(2048), dim3(128), 0, stream>>>(Rp, Np, outp);
    } else {
        _Float16* Hp = (_Float16*)ws;
        up_kernel<<<dim3(512), dim3(256), 0, stream>>>(x, wg, wu, tc1, tc2,
                                                       usp, vsp, Hp);
        down_kernel<<<dim3(256), dim3(256), 0, stream>>>(wd, tc3, Hp, outp);
        final_kernel<<<dim3(2048), dim3(128), 0, stream>>>(outp);
    }
}

// Round 11
// 228.670 us; speedup vs baseline: 1.0802x; 1.0025x over previous
//
#include <hip/hip_runtime.h>
#include <hip/hip_bf16.h>
#include <cmath>

// ---------------------------------------------------------------------------
// NPerTokenSwishGLU_Basis — fused f16-MFMA implementation (gfx950), round 18.
//
// R17 re-anchored baseline (225-229us band). Surviving model: up/down are
// pinned at ~10.4 TB/s aggregate L2/L3 streaming — time tracks BYTES
// (occupancy/barriers/unroll/prefetch all null, R8-R15). R18 is the clean
// byte-reduction test R16 botched: each block processes 2 lg groups (32 l),
// reusing every pa load for two mixes (two cf sets):
//   up:   P re-reads 8x->4x (256->128MB), total reads 512->384MB (-25%).
//   down: P3 re-reads 8x->4x (128->64MB), reads 384->320MB (-17%).
// Trap avoidance: 256 thr (not 512); Wt[2 buf][2 sub][16*584] keeps the
// proven conflict-free per-sub stride (74.75KB -> 2 blocks/CU); per-wave
// state doubled via STATIC names (aU0/aU1, xf0/xf1; rule-#20-safe);
// __launch_bounds__(256,2) -> 128-VGPR grant (demand ~110; (256,4)'s 64-cap
// spilled R15). pa loads / barriers / per-sub indexing identical to R14.
// ---------------------------------------------------------------------------

typedef _Float16 half8 __attribute__((ext_vector_type(8)));
typedef _Float16 half4 __attribute__((ext_vector_type(4)));
typedef float    f32x4 __attribute__((ext_vector_type(4)));
typedef float    f32x2 __attribute__((ext_vector_type(2)));

#define MFMA_F16  __builtin_amdgcn_mfma_f32_16x16x32_f16
#define MFMA16    __builtin_amdgcn_mfma_f32_16x16x16f16

// LDS-only barrier: drain DS ops, leave global loads in flight.
#define LDS_BARRIER()                                           \
    do {                                                        \
        asm volatile("s_waitcnt lgkmcnt(0)" ::: "memory");      \
        __builtin_amdgcn_s_barrier();                           \
    } while (0)

static constexpr size_t OFF_P1  = 0;            // 16 MiB; Rp overlay (down)
static constexpr size_t OFF_P2  = 16777216;     // 16 MiB; Np overlay (down, 1 MiB)
static constexpr size_t OFF_P3n = 17825792;     // 16 MiB at 17 MiB (after Np)
static constexpr size_t OFF_XA  = 33554432;     // 2 MiB at 32 MiB
static constexpr size_t OFF_U2  = 35651584;     // 4 MiB at 34 MiB
static constexpr size_t OFF_S   = 39845888;     // 4 MiB at 38 MiB (top 42 MiB)
static constexpr size_t WS_FAST = 54525952;     // 52 MiB (proven)

// ---------------------------------------------------------------------------
// prep (two-sided coalesced transpose), 32x32 tiles (R13):
//   z=0,1: wg/wu (K,512,1024)=[k][d][f] -> P[f][d][k]
//   z=2  : wd    (K,1024,512)=[k][f][d] -> P3[d][f][k]
// ---------------------------------------------------------------------------
__global__ __launch_bounds__(256) void prep_basis_all(
    const float* __restrict__ wg, const float* __restrict__ wu,
    const float* __restrict__ wd,
    _Float16* __restrict__ P1, _Float16* __restrict__ P2,
    _Float16* __restrict__ P3, int zoff)
{
    int z = blockIdx.y + zoff;
    const float* src = (z == 0) ? wg : (z == 1) ? wu : wd;
    _Float16*    dst = (z == 0) ? P1 : (z == 1) ? P2 : P3;
    int Amin = (z == 2) ? 1024 : 512;    // minor-dim size
    int Bmaj = (z == 2) ? 512 : 1024;    // major-dim size
    int nM = Bmaj >> 5;
    int m0 = (blockIdx.x / nM) * 32;     // minor base
    int M0 = (blockIdx.x % nM) * 32;     // major base

    __shared__ float S[16 * 1088];       // [k][row*34 + col]
    int t = threadIdx.x;

    int row = t >> 3;                    // 0..31 (minor row)
    int cg  = t & 7;                     // 0..7 (16B col group)
#pragma unroll
    for (int k = 0; k < 16; ++k) {
        f32x4 v = *(const f32x4*)(
            src + (size_t)k * Amin * Bmaj + (size_t)(m0 + row) * Bmaj + M0 + cg * 4);
        f32x2 lo = { v[0], v[1] };
        f32x2 hi = { v[2], v[3] };
        *(f32x2*)(&S[k * 1088 + row * 34 + cg * 4])     = lo;
        *(f32x2*)(&S[k * 1088 + row * 34 + cg * 4 + 2]) = hi;
    }
    __syncthreads();

    int mn = t & 31, mjq = t >> 5;
#pragma unroll
    for (int q = 0; q < 4; ++q) {
        int mj = q * 8 + mjq;
        half8 v0, v1;
#pragma unroll
        for (int k = 0; k < 8; ++k) v0[k] = (_Float16)S[k * 1088 + mn * 34 + mj];
#pragma unroll
        for (int k = 0; k < 8; ++k) v1[k] = (_Float16)S[(k + 8) * 1088 + mn * 34 + mj];
        _Float16* out = dst + ((size_t)(M0 + mj) * Amin + m0 + mn) * 16;
        *(half8*)out       = v0;
        *(half8*)(out + 8) = v1;
    }
}

// ---------------------------------------------------------------------------
// prep_x: x fp32 [b][l][d] -> XA f16 [l][d>>3][b][8]
// grid 256 = 128 l x 2 b-halves, 256 threads.
// ---------------------------------------------------------------------------
__global__ __launch_bounds__(256) void prep_x(
    const float* __restrict__ x, _Float16* __restrict__ XA)
{
    int l = blockIdx.x >> 1, bh = blockIdx.x & 1;
    __shared__ __align__(16) _Float16 XT[8][524];
    int t = threadIdx.x;

    int bl = t >> 5, q = t & 31;          // b-local 0..7, q 0..31
    int b = bh * 8 + bl;
#pragma unroll
    for (int j = 0; j < 4; ++j) {
        f32x4 v = *(const f32x4*)(x + ((size_t)(b * 128 + l) * 512 + j * 128 + q * 4));
#pragma unroll
        for (int i = 0; i < 4; ++i)
            XT[bl][j * 128 + q * 4 + i] = (_Float16)v[i];
    }
    __syncthreads();

    int c = t >> 2, bi = t & 3;           // c 0..63
#pragma unroll
    for (int s = 0; s < 2; ++s) {
        int blw = bi * 2 + s;             // 0..7
        half8 h = *(const half8*)(&XT[blw][c * 8]);
        *(half8*)(XA + (((size_t)(l * 64 + c) * 16 + bh * 8 + blw) * 8)) = h;
    }
}

// ---------------------------------------------------------------------------
// up_split (R18): 512 blocks = mh(2) x 4 lgpair x 64 f-tiles, 256 thr.
// Each block handles 2 lg groups: every pa load feeds two mixes (cf0,cf1).
// LDS: Wt[2 buf][2 sub][16*584] = 74752 B + CN 2048 B -> 2 blocks/CU.
// ---------------------------------------------------------------------------
__global__ __launch_bounds__(256, 2) void up_split(
    const _Float16* __restrict__ P1, const _Float16* __restrict__ P2,
    const _Float16* __restrict__ XA,
    const float* __restrict__ tc1, const float* __restrict__ tc2,
    const float* __restrict__ usp, const float* __restrict__ vsp,
    _Float16* __restrict__ U2, _Float16* __restrict__ S)
{
    int bid = blockIdx.x;
    int mh = bid >> 8;                  // 0: gate/u, 1: up/v
    int lgp = (bid >> 6) & 3;           // lg pair: covers lg = lgp*2, lgp*2+1
    int f0 = (bid & 63) * 16;
    int tid = threadIdx.x;
    int w = tid >> 6, lane = tid & 63;
    int n = lane & 15, kc = lane >> 4;

    const _Float16* P  = mh ? P2 : P1;
    const float*    tc = mh ? tc2 : tc1;

    __shared__ __align__(16) _Float16 Wt[2][2][16 * 584]; // [buf][sub][l*584+f*36+d]
    __shared__ float CN[512];           // softmax 32 rows; later nsq [sub][256]

    // element-unit base pointers (advance +512 per 32-d chunk)
    const _Float16* pP  = P + ((size_t)(f0 + w * 4) * 512 + n) * 16 + kc * 4;
    // XA: l stride = 8192 elems; sub1 base = +16 l = +131072
    const _Float16* pXA = XA +
        (((size_t)(lgp * 32 + w * 4) * 64 + kc) * 16 + n) * 8;

    half4 pa[4][2];
    // ---- prologue: issue pa(0); softmax + barrier cover the latency ----
#pragma unroll
    for (int fl = 0; fl < 4; ++fl)
#pragma unroll
        for (int dg = 0; dg < 2; ++dg)
            pa[fl][dg] = *(const half4*)(pP + fl * 8192 + dg * 256);
    const _Float16* qP = pP + 512;

    if (tid < 32) {
        const float* row = tc + (size_t)(lgp * 32 + tid) * 16;
        float e[16], m = -1e30f, sum = 0.f;
#pragma unroll
        for (int k = 0; k < 16; ++k) m = fmaxf(m, row[k]);
#pragma unroll
        for (int k = 0; k < 16; ++k) { e[k] = __expf(row[k] - m); sum += e[k]; }
        float r = 1.f / sum;
#pragma unroll
        for (int k = 0; k < 16; ++k) CN[tid * 16 + k] = e[k] * r;
    }
    __syncthreads();

    half4 cf0, cf1;
#pragma unroll
    for (int j = 0; j < 4; ++j) {
        cf0[j] = (_Float16)CN[n * 16 + kc * 4 + j];
        cf1[j] = (_Float16)CN[(16 + n) * 16 + kc * 4 + j];
    }
    __syncthreads();                    // CN reused for nsq at the end

    f32x4 zf = { 0.f, 0.f, 0.f, 0.f };
    f32x4 aU0[4], aU1[4];
#pragma unroll
    for (int i = 0; i < 4; ++i) { aU0[i] = zf; aU1[i] = zf; }
    float nsq0[4] = { 0.f, 0.f, 0.f, 0.f };
    float nsq1[4] = { 0.f, 0.f, 0.f, 0.f };
    half8 xf0[4], xf1[4];

#pragma unroll 1
    for (int it = 0; it < 16; ++it) {
        _Float16* W0 = &Wt[it & 1][0][0];
        _Float16* W1 = &Wt[it & 1][1][0];
        const _Float16* R0 = &Wt[(it & 1) ^ 1][0][0];
        const _Float16* R1 = &Wt[(it & 1) ^ 1][1][0];

        // ---- mix(it): each pa feeds two cf sets, K=16 MFMA ----
#pragma unroll
        for (int fl = 0; fl < 4; ++fl) {
            int f_l = w * 4 + fl;
#pragma unroll
            for (int dg = 0; dg < 2; ++dg) {
                f32x4 c0 = MFMA16(pa[fl][dg], cf0, zf, 0, 0, 0);
                nsq0[fl] += c0[0] * c0[0] + c0[1] * c0[1]
                          + c0[2] * c0[2] + c0[3] * c0[3];
                half4 h0 = { (_Float16)c0[0], (_Float16)c0[1],
                             (_Float16)c0[2], (_Float16)c0[3] };
                *(half4*)(&W0[n * 584 + f_l * 36 + dg * 16 + kc * 4]) = h0;
                f32x4 c1 = MFMA16(pa[fl][dg], cf1, zf, 0, 0, 0);
                nsq1[fl] += c1[0] * c1[0] + c1[1] * c1[1]
                          + c1[2] * c1[2] + c1[3] * c1[3];
                half4 h1 = { (_Float16)c1[0], (_Float16)c1[1],
                             (_Float16)c1[2], (_Float16)c1[3] };
                *(half4*)(&W1[n * 584 + f_l * 36 + dg * 16 + kc * 4]) = h1;
            }
        }
        // ---- issue pa(it+1) into freed regs ----
        if (it < 15) {
#pragma unroll
            for (int fl = 0; fl < 4; ++fl)
#pragma unroll
                for (int dg = 0; dg < 2; ++dg)
                    pa[fl][dg] = *(const half4*)(qP + fl * 8192 + dg * 256);
        }
        // ---- consume(it-1): both subs ----
        if (it > 0) {
#pragma unroll
            for (int li = 0; li < 4; ++li) {
                int l = w * 4 + li;
                half8 w0 = *(const half8*)(&R0[l * 584 + n * 36 + kc * 8]);
                half8 w1 = *(const half8*)(&R1[l * 584 + n * 36 + kc * 8]);
                aU0[li] = MFMA_F16(xf0[li], w0, aU0[li], 0, 0, 0);
                aU1[li] = MFMA_F16(xf1[li], w1, aU1[li], 0, 0, 0);
            }
        }
        // ---- load xf(it) for both subs (1KB dense each) ----
#pragma unroll
        for (int li = 0; li < 4; ++li) {
            xf0[li] = *(const half8*)(pXA + li * 8192);
            xf1[li] = *(const half8*)(pXA + 131072 + li * 8192);
        }
        pXA += 512;
        qP += 512;
        LDS_BARRIER();   // drain DS only; global prefetches stay in flight
    }
    // ---- tail consume (chunk 15, buffer 1) ----
#pragma unroll
    for (int li = 0; li < 4; ++li) {
        int l = w * 4 + li;
        half8 w0 = *(const half8*)(&Wt[1][0][l * 584 + n * 36 + kc * 8]);
        half8 w1 = *(const half8*)(&Wt[1][1][l * 584 + n * 36 + kc * 8]);
        aU0[li] = MFMA_F16(xf0[li], w0, aU0[li], 0, 0, 0);
        aU1[li] = MFMA_F16(xf1[li], w1, aU1[li], 0, 0, 0);
    }

    // ---- norm reduce (both subs) ----
#pragma unroll
    for (int fl = 0; fl < 4; ++fl) {
        float v0 = nsq0[fl], v1 = nsq1[fl];
        v0 += __shfl_xor(v0, 16); v0 += __shfl_xor(v0, 32);
        v1 += __shfl_xor(v1, 16); v1 += __shfl_xor(v1, 32);
        if (kc == 0) {
            CN[0 * 256 + n * 16 + w * 4 + fl] = v0;
            CN[1 * 256 + n * 16 + w * 4 + fl] = v1;
        }
    }
    __syncthreads();

    int f = f0 + n;
    float sc = mh ? (fabsf(vsp[f]) * 22.627416997969522f)   // vs = |vsp|*sqrt(512)
                  : fabsf(usp[f]);                          // us = |usp|
    _Float16* Out = mh ? S : U2;
#pragma unroll
    for (int li = 0; li < 4; ++li) {
        int lgl0 = lgp * 32 + w * 4 + li;
        int lgl1 = lgl0 + 16;
        float r0 = 1.f / fmaxf(sqrtf(CN[0 * 256 + (w * 4 + li) * 16 + n]), 1e-12f);
        float r1 = 1.f / fmaxf(sqrtf(CN[1 * 256 + (w * 4 + li) * 16 + n]), 1e-12f);
#pragma unroll
        for (int i = 0; i < 4; ++i) {
            float v0 = aU0[li][i] * r0 * sc;
            float v1 = aU1[li][i] * r1 * sc;
            if (mh) {
                v0 = v0 / (1.f + __expf(-v0));
                v1 = v1 / (1.f + __expf(-v1));
            }
            // layout [l][f>>3][b][8]
            Out[(((size_t)lgl0 * 128 + (f >> 3)) * 16 + kc * 4 + i) * 8 + (f & 7)] =
                (_Float16)v0;
            Out[(((size_t)lgl1 * 128 + (f >> 3)) * 16 + kc * 4 + i) * 8 + (f & 7)] =
                (_Float16)v1;
        }
    }
}

// ---------------------------------------------------------------------------
// down_fast (R18): 512 blocks = 4 zh x 4 lgpair x 32 d-tiles, 256 thr.
// Each block handles 2 lg groups: every P3 load feeds two mixes.
// LDS: Wt[2][2][16*584] + CN 2048 -> 2 blocks/CU. __launch_bounds__(256,2).
// ---------------------------------------------------------------------------
__global__ __launch_bounds__(256, 2) void down_fast(
    const _Float16* __restrict__ P3, const float* __restrict__ tc3,
    const _Float16* __restrict__ S, const _Float16* __restrict__ U2,
    float* __restrict__ Rp, float* __restrict__ Np)
{
    int bid = blockIdx.x;
    int zh = bid >> 7;                  // 0..3
    int lgp = (bid >> 5) & 3;
    int d0 = (bid & 31) * 16;
    int tid = threadIdx.x;
    int w = tid >> 6, lane = tid & 63;
    int n = lane & 15, kc = lane >> 4;

    __shared__ __align__(16) _Float16 Wt[2][2][16 * 584]; // [buf][sub][l*584+d*36+f]
    __shared__ float CN[512];

    // element-unit base pointers (advance +512 per 32-f chunk)
    const _Float16* pP3 = P3 + ((size_t)(d0 + w * 4) * 1024 + zh * 256 + n) * 16 + kc * 4;
    // Hp-layout streams: l stride = 16384 elems; sub1 base = +16 l = +262144
    size_t hoff = (((size_t)(lgp * 32 + w * 4) * 128 + zh * 32 + kc) * 16 + n) * 8;
    const _Float16* pS = S + hoff;
    const _Float16* pU = U2 + hoff;

    half4 pa[4][2];
    // ---- prologue: issue pa(0) ----
#pragma unroll
    for (int dl = 0; dl < 4; ++dl)
#pragma unroll
        for (int fg = 0; fg < 2; ++fg)
            pa[dl][fg] = *(const half4*)(pP3 + dl * 16384 + fg * 256);
    const _Float16* qP3 = pP3 + 512;

    if (tid < 32) {
        const float* row = tc3 + (size_t)(lgp * 32 + tid) * 16;
        float e[16], m = -1e30f, sum = 0.f;
#pragma unroll
        for (int k = 0; k < 16; ++k) m = fmaxf(m, row[k]);
#pragma unroll
        for (int k = 0; k < 16; ++k) { e[k] = __expf(row[k] - m); sum += e[k]; }
        float r = 1.f / sum;
#pragma unroll
        for (int k = 0; k < 16; ++k) CN[tid * 16 + k] = e[k] * r;
    }
    __syncthreads();

    half4 cf30, cf31;
#pragma unroll
    for (int j = 0; j < 4; ++j) {
        cf30[j] = (_Float16)CN[n * 16 + kc * 4 + j];
        cf31[j] = (_Float16)CN[(16 + n) * 16 + kc * 4 + j];
    }
    __syncthreads();                    // CN reused for nsq

    f32x4 zf = { 0.f, 0.f, 0.f, 0.f };
    f32x4 aO0[4], aO1[4];
#pragma unroll
    for (int i = 0; i < 4; ++i) { aO0[i] = zf; aO1[i] = zf; }
    float nsq0[4] = { 0.f, 0.f, 0.f, 0.f };
    float nsq1[4] = { 0.f, 0.f, 0.f, 0.f };
    half8 hf0[4], hf1[4];

#pragma unroll 1
    for (int it = 0; it < 8; ++it) {
        _Float16* W0 = &Wt[it & 1][0][0];
        _Float16* W1 = &Wt[it & 1][1][0];
        const _Float16* R0 = &Wt[(it & 1) ^ 1][0][0];
        const _Float16* R1 = &Wt[(it & 1) ^ 1][1][0];

        // ---- mix(it): each pa feeds two cf sets ----
#pragma unroll
        for (int dl = 0; dl < 4; ++dl) {
            int d_l = w * 4 + dl;
#pragma unroll
            for (int fg = 0; fg < 2; ++fg) {
                f32x4 c0 = MFMA16(pa[dl][fg], cf30, zf, 0, 0, 0);
                nsq0[dl] += c0[0] * c0[0] + c0[1] * c0[1]
                          + c0[2] * c0[2] + c0[3] * c0[3];
                half4 h0 = { (_Float16)c0[0], (_Float16)c0[1],
                             (_Float16)c0[2], (_Float16)c0[3] };
                *(half4*)(&W0[n * 584 + d_l * 36 + fg * 16 + kc * 4]) = h0;
                f32x4 c1 = MFMA16(pa[dl][fg], cf31, zf, 0, 0, 0);
                nsq1[dl] += c1[0] * c1[0] + c1[1] * c1[1]
                          + c1[2] * c1[2] + c1[3] * c1[3];
                half4 h1 = { (_Float16)c1[0], (_Float16)c1[1],
                             (_Float16)c1[2], (_Float16)c1[3] };
                *(half4*)(&W1[n * 584 + d_l * 36 + fg * 16 + kc * 4]) = h1;
            }
        }
        // ---- issue pa(it+1) ----
        if (it < 7) {
#pragma unroll
            for (int dl = 0; dl < 4; ++dl)
#pragma unroll
                for (int fg = 0; fg < 2; ++fg)
                    pa[dl][fg] = *(const half4*)(qP3 + dl * 16384 + fg * 256);
        }
        // ---- consume(it-1): both subs ----
        if (it > 0) {
#pragma unroll
            for (int li = 0; li < 4; ++li) {
                int l = w * 4 + li;
                half8 w0 = *(const half8*)(&R0[l * 584 + n * 36 + kc * 8]);
                half8 w1 = *(const half8*)(&R1[l * 584 + n * 36 + kc * 8]);
                aO0[li] = MFMA_F16(hf0[li], w0, aO0[li], 0, 0, 0);
                aO1[li] = MFMA_F16(hf1[li], w1, aO1[li], 0, 0, 0);
            }
        }
        // ---- load hf(it) = S*U2 for both subs ----
#pragma unroll
        for (int li = 0; li < 4; ++li) {
            half8 s0 = *(const half8*)(pS + li * 16384);
            half8 u0 = *(const half8*)(pU + li * 16384);
            hf0[li] = s0 * u0;
            half8 s1 = *(const half8*)(pS + 262144 + li * 16384);
            half8 u1 = *(const half8*)(pU + 262144 + li * 16384);
            hf1[li] = s1 * u1;
        }
        pS += 512;
        pU += 512;
        qP3 += 512;
        LDS_BARRIER();
    }
    // ---- tail consume (chunk 7, buffer 1) ----
#pragma unroll
    for (int li = 0; li < 4; ++li) {
        int l = w * 4 + li;
        half8 w0 = *(const half8*)(&Wt[1][0][l * 584 + n * 36 + kc * 8]);
        half8 w1 = *(const half8*)(&Wt[1][1][l * 584 + n * 36 + kc * 8]);
        aO0[li] = MFMA_F16(hf0[li], w0, aO0[li], 0, 0, 0);
        aO1[li] = MFMA_F16(hf1[li], w1, aO1[li], 0, 0, 0);
    }

    // ---- norm partials (both subs) ----
#pragma unroll
    for (int dl = 0; dl < 4; ++dl) {
        float v0 = nsq0[dl], v1 = nsq1[dl];
        v0 += __shfl_xor(v0, 16); v0 += __shfl_xor(v0, 32);
        v1 += __shfl_xor(v1, 16); v1 += __shfl_xor(v1, 32);
        if (kc == 0) {
            Np[(size_t)zh * 65536 + (size_t)(lgp * 32 + n) * 512 + d0 + w * 4 + dl] = v0;
            Np[(size_t)zh * 65536 + (size_t)(lgp * 32 + 16 + n) * 512 + d0 + w * 4 + dl] = v1;
        }
    }
#pragma unroll
    for (int li = 0; li < 4; ++li) {
        int lgl0 = lgp * 32 + w * 4 + li;
        int lgl1 = lgl0 + 16;
#pragma unroll
        for (int i = 0; i < 4; ++i) {
            Rp[(size_t)zh * 1048576 +
               ((size_t)(kc * 4 + i) * 128 + lgl0) * 512 + d0 + n] = aO0[li][i];
            Rp[(size_t)zh * 1048576 +
               ((size_t)(kc * 4 + i) * 128 + lgl1) * 512 + d0 + n] = aO1[li][i];
        }
    }
}

// ---------------------------------------------------------------------------
__global__ __launch_bounds__(128) void final_combine(
    const float* __restrict__ Rp, const float* __restrict__ Np,
    float* __restrict__ out)
{
    int rid = blockIdx.x;              // b*128 + l
    int l = rid & 127;
    int t = threadIdx.x;
    f32x4 r = { 0.f, 0.f, 0.f, 0.f };
    f32x4 nn = { 0.f, 0.f, 0.f, 0.f };
#pragma unroll
    for (int zh = 0; zh < 4; ++zh) {
        f32x4 rz = *(const f32x4*)(Rp + (size_t)zh * 1048576 + (size_t)rid * 512 + t * 4);
        f32x4 nz = *(const f32x4*)(Np + (size_t)zh * 65536 + (size_t)l * 512 + t * 4);
#pragma unroll
        for (int j = 0; j < 4; ++j) { r[j] += rz[j]; nn[j] += nz[j]; }
    }
    f32x4 y;
#pragma unroll
    for (int j = 0; j < 4; ++j) {
        float rr = 1.f / fmaxf(sqrtf(fmaxf(nn[j], 0.f)), 1e-12f);
        y[j] = r[j] * rr;
    }
    float s = y[0] * y[0] + y[1] * y[1] + y[2] * y[2] + y[3] * y[3];
#pragma unroll
    for (int off = 32; off > 0; off >>= 1) s += __shfl_down(s, off);
    __shared__ float sred[2];
    if ((t & 63) == 0) sred[t >> 6] = s;
    __syncthreads();
    float rr = 1.f / fmaxf(sqrtf(sred[0] + sred[1]), 1e-12f);
    f32x4 o = { y[0] * rr, y[1] * rr, y[2] * rr, y[3] * rr };
    *(f32x4*)(out + (size_t)rid * 512 + t * 4) = o;
}

// ===========================================================================
// SLOW FALLBACK (round-2 kernels, proven) — used when ws_size < WS_FAST
// ===========================================================================
__global__ __launch_bounds__(256) void up_kernel(
    const float* __restrict__ x,
    const float* __restrict__ wg, const float* __restrict__ wu,
    const float* __restrict__ tc1, const float* __restrict__ tc2,
    const float* __restrict__ usp, const float* __restrict__ vsp,
    _Float16* __restrict__ Hp)
{
    int lg = blockIdx.x >> 6;
    int f0 = (blockIdx.x & 63) * 16;
    int tid = threadIdx.x;
    int w = tid >> 6, lane = tid & 63;
    int n = lane & 15, kc = lane >> 4;

    __shared__ __align__(16) _Float16 Xt[256 * 40];
    __shared__ __align__(16) _Float16 Bh[32 * 16 * 24];
    __shared__ __align__(16) _Float16 Wt[16 * 528];
    __shared__ float CN[2 * 16 * 16];

    if (tid < 32) {
        int s = tid >> 4, ll = tid & 15;
        const float* row = (s ? tc2 : tc1) + (size_t)(lg * 16 + ll) * 16;
        float e[16], m = -1e30f, sum = 0.f;
#pragma unroll
        for (int k = 0; k < 16; ++k) m = fmaxf(m, row[k]);
#pragma unroll
        for (int k = 0; k < 16; ++k) { e[k] = __expf(row[k] - m); sum += e[k]; }
        float r = 1.f / sum;
#pragma unroll
        for (int k = 0; k < 16; ++k) CN[s * 256 + ll * 16 + k] = e[k] * r;
    }
    __syncthreads();

    half8 cf1 = { 0, 0, 0, 0, 0, 0, 0, 0 };
    half8 cf2 = { 0, 0, 0, 0, 0, 0, 0, 0 };
    if (kc < 2) {
#pragma unroll
        for (int j = 0; j < 8; ++j) {
            cf1[j] = (_Float16)CN[0 * 256 + n * 16 + kc * 8 + j];
            cf2[j] = (_Float16)CN[1 * 256 + n * 16 + kc * 8 + j];
        }
    }

    f32x4 zf = { 0.f, 0.f, 0.f, 0.f };
    f32x4 aU[4], aV[4];
#pragma unroll
    for (int i = 0; i < 4; ++i) { aU[i] = zf; aV[i] = zf; }
    float nsqU[4] = { 0.f, 0.f, 0.f, 0.f };
    float nsqV[4] = { 0.f, 0.f, 0.f, 0.f };

    for (int it = 0; it < 16; ++it) {
        int d0 = it * 32;
#pragma unroll
        for (int p = 0; p < 8; ++p) {
            int r = p * 32 + (tid >> 3);
            int fj = tid & 7;
            int ll = r >> 4, b = r & 15;
            f32x4 v = *(const f32x4*)(
                x + ((size_t)(b * 128 + lg * 16 + ll) * 512 + d0 + fj * 4));
            half4 h = { (_Float16)v[0], (_Float16)v[1],
                        (_Float16)v[2], (_Float16)v[3] };
            *(half4*)(&Xt[r * 40 + fj * 4]) = h;
        }
#pragma unroll
        for (int p = 0; p < 8; ++p) {
            int idx = p * 256 + tid;
            int q = idx & 3, dd = (idx >> 2) & 31, k = idx >> 7;
            f32x4 v = *(const f32x4*)(
                wg + ((size_t)k * 512 + d0 + dd) * 1024 + f0 + q * 4);
#pragma unroll
            for (int j = 0; j < 4; ++j)
                Bh[(dd * 16 + q * 4 + j) * 24 + k] = (_Float16)v[j];
        }
        __syncthreads();
#pragma unroll
        for (int fl = 0; fl < 4; ++fl) {
            int f_l = w * 4 + fl;
#pragma unroll
            for (int dg = 0; dg < 2; ++dg) {
                half8 a = { 0, 0, 0, 0, 0, 0, 0, 0 };
                if (kc < 2)
                    a = *(const half8*)(&Bh[((dg * 16 + n) * 16 + f_l) * 24 + kc * 8]);
                f32x4 cw = MFMA_F16(a, cf1, zf, 0, 0, 0);
                nsqU[fl] += cw[0] * cw[0] + cw[1] * cw[1]
                          + cw[2] * cw[2] + cw[3] * cw[3];
                half4 h4 = { (_Float16)cw[0], (_Float16)cw[1],
                             (_Float16)cw[2], (_Float16)cw[3] };
                *(half4*)(&Wt[n * 528 + f_l * 32 + dg * 16 + kc * 4]) = h4;
            }
        }
        __syncthreads();
#pragma unroll
        for (int li = 0; li < 4; ++li) {
            int l = w * 4 + li;
            half8 xf = *(const half8*)(&Xt[(l * 16 + n) * 40 + kc * 8]);
            half8 wf = *(const half8*)(&Wt[l * 528 + n * 32 + kc * 8]);
            aU[li] = MFMA_F16(xf, wf, aU[li], 0, 0, 0);
        }
#pragma unroll
        for (int p = 0; p < 8; ++p) {
            int idx = p * 256 + tid;
            int q = idx & 3, dd = (idx >> 2) & 31, k = idx >> 7;
            f32x4 v = *(const f32x4*)(
                wu + ((size_t)k * 512 + d0 + dd) * 1024 + f0 + q * 4);
#pragma unroll
            for (int j = 0; j < 4; ++j)
                Bh[(dd * 16 + q * 4 + j) * 24 + k] = (_Float16)v[j];
        }
        __syncthreads();
#pragma unroll
        for (int fl = 0; fl < 4; ++fl) {
            int f_l = w * 4 + fl;
#pragma unroll
            for (int dg = 0; dg < 2; ++dg) {
                half8 a = { 0, 0, 0, 0, 0, 0, 0, 0 };
                if (kc < 2)
                    a = *(const half8*)(&Bh[((dg * 16 + n) * 16 + f_l) * 24 + kc * 8]);
                f32x4 cw = MFMA_F16(a, cf2, zf, 0, 0, 0);
                nsqV[fl] += cw[0] * cw[0] + cw[1] * cw[1]
                          + cw[2] * cw[2] + cw[3] * cw[3];
                half4 h4 = { (_Float16)cw[0], (_Float16)cw[1],
                             (_Float16)cw[2], (_Float16)cw[3] };
                *(half4*)(&Wt[n * 528 + f_l * 32 + dg * 16 + kc * 4]) = h4;
            }
        }
        __syncthreads();
#pragma unroll
        for (int li = 0; li < 4; ++li) {
            int l = w * 4 + li;
            half8 xf = *(const half8*)(&Xt[(l * 16 + n) * 40 + kc * 8]);
            half8 wf = *(const half8*)(&Wt[l * 528 + n * 32 + kc * 8]);
            aV[li] = MFMA_F16(xf, wf, aV[li], 0, 0, 0);
        }
        __syncthreads();
    }

#pragma unroll
    for (int fl = 0; fl < 4; ++fl) {
        float vU = nsqU[fl], vV = nsqV[fl];
        vU += __shfl_xor(vU, 16); vU += __shfl_xor(vU, 32);
        vV += __shfl_xor(vV, 16); vV += __shfl_xor(vV, 32);
        if (kc == 0) {
            CN[0 * 256 + n * 16 + w * 4 + fl] = vU;
            CN[1 * 256 + n * 16 + w * 4 + fl] = vV;
        }
    }
    __syncthreads();

    int f = f0 + n;
    float usv = fabsf(usp[f]);
    float vsv = fabsf(vsp[f]) * 22.627416997969522f;
#pragma unroll
    for (int li = 0; li < 4; ++li) {
        int lgl = lg * 16 + w * 4 + li;
        float r1 = 1.f / fmaxf(sqrtf(CN[0 * 256 + (w * 4 + li) * 16 + n]), 1e-12f);
        float r2 = 1.f / fmaxf(sqrtf(CN[1 * 256 + (w * 4 + li) * 16 + n]), 1e-12f);
#pragma unroll
        for (int i = 0; i < 4; ++i) {
            float u = aU[li][i] * r1;
            float v = aV[li][i] * r2;
            float zz = vsv * v;
            float sil = zz / (1.f + __expf(-zz));
            float h = sil * (usv * u);
            Hp[((size_t)lgl * 16 + kc * 4 + i) * 1024 + f] = (_Float16)h;
        }
    }
}

__global__ __launch_bounds__(256) void down_kernel(
    const float* __restrict__ wd, const float* __restrict__ tc3,
    const _Float16* __restrict__ Hp, float* __restrict__ out)
{
    int lg = blockIdx.x >> 5;
    int d0 = (blockIdx.x & 31) * 16;
    int tid = threadIdx.x;
    int w = tid >> 6, lane = tid & 63;
    int n = lane & 15, kc = lane >> 4;

    __shared__ __align__(16) _Float16 Ht[256 * 40];
    __shared__ __align__(16) _Float16 Bh[32 * 16 * 24];
    __shared__ __align__(16) _Float16 Wt[16 * 528];
    __shared__ float CN[16 * 16];

    if (tid < 16) {
        const float* row = tc3 + (size_t)(lg * 16 + tid) * 16;
        float e[16], m = -1e30f, sum = 0.f;
#pragma unroll
        for (int k = 0; k < 16; ++k) m = fmaxf(m, row[k]);
#pragma unroll
        for (int k = 0; k < 16; ++k) { e[k] = __expf(row[k] - m); sum += e[k]; }
        float r = 1.f / sum;
#pragma unroll
        for (int k = 0; k < 16; ++k) CN[tid * 16 + k] = e[k] * r;
    }
    __syncthreads();

    half8 cf3 = { 0, 0, 0, 0, 0, 0, 0, 0 };
    if (kc < 2) {
#pragma unroll
        for (int j = 0; j < 8; ++j)
            cf3[j] = (_Float16)CN[n * 16 + kc * 8 + j];
    }

    f32x4 zf = { 0.f, 0.f, 0.f, 0.f };
    f32x4 aO[4];
#pragma unroll
    for (int i = 0; i < 4; ++i) aO[i] = zf;
    float nsqD[4] = { 0.f, 0.f, 0.f, 0.f };

    for (int it = 0; it < 32; ++it) {
        int f0 = it * 32;
#pragma unroll
        for (int p = 0; p < 8; ++p) {
            int r = p * 32 + (tid >> 3);
            int hj = tid & 7;
            int ll = r >> 4, b = r & 15;
            half4 v = *(const half4*)(
                Hp + ((size_t)(lg * 16 + ll) * 16 + b) * 1024 + f0 + hj * 4);
            *(half4*)(&Ht[r * 40 + hj * 4]) = v;
        }
#pragma unroll
        for (int p = 0; p < 8; ++p) {
            int idx = p * 256 + tid;
            int q = idx & 3, ff = (idx >> 2) & 31, k = idx >> 7;
            f32x4 v = *(const f32x4*)(
                wd + ((size_t)k * 1024 + f0 + ff) * 512 + d0 + q * 4);
#pragma unroll
            for (int j = 0; j < 4; ++j)
                Bh[(ff * 16 + q * 4 + j) * 24 + k] = (_Float16)v[j];
        }
        __syncthreads();
#pragma unroll
        for (int dl = 0; dl < 4; ++dl) {
            int d_l = w * 4 + dl;
#pragma unroll
            for (int fg = 0; fg < 2; ++fg) {
                half8 a = { 0, 0, 0, 0, 0, 0, 0, 0 };
                if (kc < 2)
                    a = *(const half8*)(&Bh[((fg * 16 + n) * 16 + d_l) * 24 + kc * 8]);
                f32x4 cw = MFMA_F16(a, cf3, zf, 0, 0, 0);
                nsqD[dl] += cw[0] * cw[0] + cw[1] * cw[1]
                          + cw[2] * cw[2] + cw[3] * cw[3];
                half4 h4 = { (_Float16)cw[0], (_Float16)cw[1],
                             (_Float16)cw[2], (_Float16)cw[3] };
                *(half4*)(&Wt[n * 528 + d_l * 32 + fg * 16 + kc * 4]) = h4;
            }
        }
        __syncthreads();
#pragma unroll
        for (int li = 0; li < 4; ++li) {
            int l = w * 4 + li;
            half8 hf = *(const half8*)(&Ht[(l * 16 + n) * 40 + kc * 8]);
            half8 wf = *(const half8*)(&Wt[l * 528 + n * 32 + kc * 8]);
            aO[li] = MFMA_F16(hf, wf, aO[li], 0, 0, 0);
        }
        __syncthreads();
    }

#pragma unroll
    for (int dl = 0; dl < 4; ++dl) {
        float v = nsqD[dl];
        v += __shfl_xor(v, 16); v += __shfl_xor(v, 32);
        if (kc == 0) CN[n * 16 + w * 4 + dl] = v;
    }
    __syncthreads();

#pragma unroll
    for (int li = 0; li < 4; ++li) {
        int lgl = lg * 16 + w * 4 + li;
        float r3 = 1.f / fmaxf(sqrtf(CN[(w * 4 + li) * 16 + n]), 1e-12f);
#pragma unroll
        for (int i = 0; i < 4; ++i)
            out[((size_t)(kc * 4 + i) * 128 + lgl) * 512 + d0 + n] = aO[li][i] * r3;
    }
}

__global__ __launch_bounds__(128) void final_kernel(float* __restrict__ out)
{
    int rid = blockIdx.x;
    int t = threadIdx.x;
    f32x4 y = *(const f32x4*)(out + (size_t)rid * 512 + t * 4);
    float s = y[0] * y[0] + y[1] * y[1] + y[2] * y[2] + y[3] * y[3];
#pragma unroll
    for (int off = 32; off > 0; off >>= 1) s += __shfl_down(s, off);
    __shared__ float sred[2];
    if ((t & 63) == 0) sred[t >> 6] = s;
    __syncthreads();
    float rr = 1.f / fmaxf(sqrtf(sred[0] + sred[1]), 1e-12f);
    f32x4 o = { y[0] * rr, y[1] * rr, y[2] * rr, y[3] * rr };
    *(f32x4*)(out + (size_t)rid * 512 + t * 4) = o;
}

// ---------------------------------------------------------------------------
extern "C" void kernel_launch(void* const* d_in, const int* in_sizes, int n_in,
                              void* d_out, int out_size, void* d_ws, size_t ws_size,
                              hipStream_t stream)
{
    (void)in_sizes; (void)n_in; (void)out_size;
    const float* x   = (const float*)d_in[0];
    const float* wg  = (const float*)d_in[1];
    const float* wu  = (const float*)d_in[2];
    const float* wd  = (const float*)d_in[3];
    const float* tc1 = (const float*)d_in[4];
    const float* tc2 = (const float*)d_in[5];
    const float* tc3 = (const float*)d_in[6];
    const float* usp = (const float*)d_in[7];
    const float* vsp = (const float*)d_in[8];
    float* outp = (float*)d_out;
    char* ws = (char*)d_ws;

    if (ws_size >= WS_FAST) {
        _Float16* P1  = (_Float16*)(ws + OFF_P1);
        _Float16* P2  = (_Float16*)(ws + OFF_P2);
        _Float16* P3n = (_Float16*)(ws + OFF_P3n);  // 17..33 MiB (after Np)
        _Float16* XA  = (_Float16*)(ws + OFF_XA);   // 32..34 MiB
        _Float16* U2  = (_Float16*)(ws + OFF_U2);   // 34..38 MiB
        _Float16* S   = (_Float16*)(ws + OFF_S);    // 38..42 MiB
        float* Rp = (float*)(ws + OFF_P1);   // overlays P1 (dead after up)
        float* Np = (float*)(ws + OFF_P2);   // 16..17 MiB (P2 dead after up)
        prep_basis_all<<<dim3(512, 2), dim3(256), 0, stream>>>(
            wg, wu, wd, P1, P2, P3n, 0);                   // P1, P2
        prep_x<<<dim3(256), dim3(256), 0, stream>>>(x, XA);
        up_split<<<dim3(512), dim3(256), 0, stream>>>(P1, P2, XA, tc1, tc2,
                                                      usp, vsp, U2, S);
        prep_basis_all<<<dim3(512, 1), dim3(256), 0, stream>>>(
            wg, wu, wd, P1, P2, P3n, 2);                   // P3 at 17 MiB
        down_fast<<<dim3(512), dim3(256), 0, stream>>>(P3n, tc3, S, U2, Rp, Np);
        final_combine<<<dim3(2048), dim3(128), 0, stream>>>(Rp, Np, outp);
    } else {
        _Float16* Hp = (_Float16*)ws;
        up_kernel<<<dim3(512), dim3(256), 0, stream>>>(x, wg, wu, tc1, tc2,
                                                       usp, vsp, Hp);
        down_kernel<<<dim3(256), dim3(256), 0, stream>>>(wd, tc3, Hp, outp);
        final_kernel<<<dim3(2048), dim3(128), 0, stream>>>(outp);
    }
}